// Round 3
// baseline (4809.575 us; speedup 1.0000x reference)
//
#include <hip/hip_runtime.h>
#include <hip/hip_bf16.h>
#include <math.h>

#define N_USERS 100000
#define N_ITEMS 50000
#define N_NODES 150000
#define DD 64
#define NI 128
#define E_G 3200000
#define EU 1600000
#define EI 800000

__device__ __forceinline__ float invdeg(float d){
  return d > 0.f ? rsqrtf(fmaxf(d, 1e-12f)) : 0.f;
}

// cur = total = concat(feat_user, feat_item)
__global__ void k_init(const float* __restrict__ fu, const float* __restrict__ fi,
                       float* __restrict__ cur, float* __restrict__ total){
  int i = blockIdx.x*256 + threadIdx.x;
  if (i >= N_NODES*DD) return;
  float v = (i < N_USERS*DD) ? fu[i] : fi[i - N_USERS*DD];
  cur[i] = v; total[i] = v;
}

// gnn[idx0] += val * cur[idx1]   (edge x dim parallel)
__global__ void k_spmm(const int* __restrict__ gi, const float* __restrict__ gv,
                       const float* __restrict__ cur, float* __restrict__ gnn){
  long t = (long)blockIdx.x*256 + threadIdx.x;
  if (t >= (long)E_G*DD) return;
  int e = (int)(t >> 6), d = (int)(t & 63);
  int i0 = gi[e], i1 = gi[E_G + e];
  float val = gv[e];
  atomicAdd(&gnn[i0*DD + d], val * cur[i1*DD + d]);
}

// per-row: p = softmax(row @ intent); o = p @ intent^T;
// cur = gnn + o + cur; total += cur.  One wave per row.
__global__ __launch_bounds__(256) void k_intent(const float* __restrict__ intent,
        const float* __restrict__ gnn, float* __restrict__ cur, float* __restrict__ total,
        int base, int nrows){
  __shared__ float sInt[64*129];
  __shared__ float sP[4*128];
  int tid = threadIdx.x;
  for (int i = tid; i < 64*128; i += 256)
    sInt[(i>>7)*129 + (i&127)] = intent[i];
  __syncthreads();
  int wv = tid >> 6, lane = tid & 63;
  int r = blockIdx.x*4 + wv;
  bool valid = r < nrows;
  int row = base + (valid ? r : 0);
  float rv = cur[row*DD + lane];
  float w0 = 0.f, w1 = 0.f;
  for (int d = 0; d < 64; ++d){
    float rd = __shfl(rv, d, 64);
    w0 += rd * sInt[d*129 + lane];
    w1 += rd * sInt[d*129 + 64 + lane];
  }
  float mx = fmaxf(w0, w1);
  for (int off = 32; off; off >>= 1) mx = fmaxf(mx, __shfl_xor(mx, off, 64));
  float e0 = __expf(w0 - mx), e1 = __expf(w1 - mx);
  float s = e0 + e1;
  for (int off = 32; off; off >>= 1) s += __shfl_xor(s, off, 64);
  float inv_s = 1.f / s;
  sP[wv*128 + lane]      = e0 * inv_s;
  sP[wv*128 + 64 + lane] = e1 * inv_s;
  __syncthreads();
  float o = 0.f;
  for (int j = 0; j < 128; ++j)
    o += sP[wv*128 + j] * sInt[lane*129 + j];
  if (valid){
    float cn = gnn[row*DD + lane] + o + rv;
    cur[row*DD + lane] = cn;
    total[row*DD + lane] += cn;
  }
}

__global__ void k_deg(const int* __restrict__ src, const int* __restrict__ dst,
                      int ne, float* __restrict__ dout, float* __restrict__ din){
  int e = blockIdx.x*256 + threadIdx.x;
  if (e >= ne) return;
  atomicAdd(&dout[src[e]], 1.f);
  atomicAdd(&din[dst[e]], 1.f);
}

// z[dst] += invsqrt(deg_out[src]) * h[src]
__global__ void k_scatter(const int* __restrict__ src, const int* __restrict__ dst,
                          int ne, const float* __restrict__ h, const float* __restrict__ dout,
                          float* __restrict__ z){
  long t = (long)blockIdx.x*256 + threadIdx.x;
  if (t >= (long)ne*DD) return;
  int e = (int)(t >> 6), d = (int)(t & 63);
  int s = src[e], dt = dst[e];
  float w = invdeg(dout[s]);
  atomicAdd(&z[dt*DD + d], w * h[s*DD + d]);
}

// scale z in place by invsqrt(deg_in); compute w[n,m]=tanh(z@W1+b1)@w2; accumulate sums
__global__ __launch_bounds__(256) void k_sem(const float* __restrict__ W1, const float* __restrict__ b1,
        const float* __restrict__ w2, const float* __restrict__ din,
        float* __restrict__ z, int nn, float* __restrict__ wsum){
  __shared__ float sW[64*129];
  __shared__ float sB[128], sV[128];
  __shared__ float sAcc[8];
  int tid = threadIdx.x;
  for (int i = tid; i < 64*128; i += 256) sW[(i>>7)*129 + (i&127)] = W1[i];
  if (tid < 128){ sB[tid] = b1[tid]; sV[tid] = w2[tid]; }
  __syncthreads();
  int wv = tid >> 6, lane = tid & 63;
  int n = blockIdx.x*4 + wv;
  bool valid = n < nn;
  int nc = valid ? n : 0;
  float wm[2];
  for (int m = 0; m < 2; ++m){
    float inv_in = invdeg(din[m*nn + nc]);
    long zi = (long)m*nn*DD + (long)nc*DD + lane;
    float zv = z[zi] * inv_in;
    if (valid) z[zi] = zv;
    float t0 = sB[lane], t1 = sB[64 + lane];
    for (int d = 0; d < 64; ++d){
      float zd = __shfl(zv, d, 64);
      t0 += zd * sW[d*129 + lane];
      t1 += zd * sW[d*129 + 64 + lane];
    }
    float v = tanhf(t0)*sV[lane] + tanhf(t1)*sV[64 + lane];
    for (int off = 32; off; off >>= 1) v += __shfl_xor(v, off, 64);
    wm[m] = valid ? v : 0.f;
  }
  if (lane == 0){ sAcc[wv*2] = wm[0]; sAcc[wv*2 + 1] = wm[1]; }
  __syncthreads();
  if (tid == 0){
    atomicAdd(&wsum[0], sAcc[0] + sAcc[2] + sAcc[4] + sAcc[6]);
    atomicAdd(&wsum[1], sAcc[1] + sAcc[3] + sAcc[5] + sAcc[7]);
  }
}

__global__ void k_beta(const float* __restrict__ wsum, float* __restrict__ beta){
  if (threadIdx.x == 0 && blockIdx.x == 0){
    float u0 = wsum[0] / (float)N_USERS, u1 = wsum[1] / (float)N_USERS;
    float m = fmaxf(u0, u1);
    float e0 = __expf(u0 - m), e1 = __expf(u1 - m);
    beta[0] = e0/(e0+e1); beta[1] = e1/(e0+e1);
    float i0 = wsum[2] / (float)N_ITEMS, i1 = wsum[3] / (float)N_ITEMS;
    m = fmaxf(i0, i1);
    e0 = __expf(i0 - m); e1 = __expf(i1 - m);
    beta[2] = e0/(e0+e1); beta[3] = e1/(e0+e1);
  }
}

__global__ void k_final(const float* __restrict__ total, const float* __restrict__ z_u,
                        const float* __restrict__ z_i, const float* __restrict__ beta,
                        float* __restrict__ out){
  int i = blockIdx.x*256 + threadIdx.x;
  if (i >= N_NODES*DD) return;
  float h;
  if (i < N_USERS*DD) h = beta[0]*z_u[i] + beta[1]*z_u[N_USERS*DD + i];
  else {
    int j = i - N_USERS*DD;
    h = beta[2]*z_i[j] + beta[3]*z_i[N_ITEMS*DD + j];
  }
  out[i] = 0.5f*total[i] + 0.5f*h;
}

extern "C" void kernel_launch(void* const* d_in, const int* in_sizes, int n_in,
                              void* d_out, int out_size, void* d_ws, size_t ws_size,
                              hipStream_t stream) {
  const int*   G_idx = (const int*)d_in[0];
  const float* G_val = (const float*)d_in[1];
  const float* fu    = (const float*)d_in[2];
  const float* fi    = (const float*)d_in[3];
  const float* u_int = (const float*)d_in[4];
  const float* i_int = (const float*)d_in[5];
  const int*   mp_u  = (const int*)d_in[6];
  const int*   mp_i  = (const int*)d_in[7];
  const float* uW1   = (const float*)d_in[8];
  const float* ub1   = (const float*)d_in[9];
  const float* uw2   = (const float*)d_in[10];
  const float* iW1   = (const float*)d_in[11];
  const float* ib1   = (const float*)d_in[12];
  const float* iw2   = (const float*)d_in[13];
  float* out = (float*)d_out;

  float* ws    = (float*)d_ws;
  float* cur   = ws;                       // 9.6M
  float* total = cur   + 9600000;          // 9.6M
  float* gnn   = total + 9600000;          // 9.6M
  float* z_u   = gnn   + 9600000;          // 2 * 6.4M
  float* z_i   = z_u   + 12800000;         // 2 * 3.2M
  float* deg_u = z_i   + 6400000;          // out[2][NU], in[2][NU] = 400k
  float* deg_i = deg_u + 400000;           // out[2][NI_n], in[2][NI_n] = 200k
  float* wsum  = deg_i + 200000;           // 4
  float* beta  = wsum  + 4;                // 4

  // zero gnn .. wsum (contiguous)
  size_t zero_f = 9600000 + 12800000 + 6400000 + 400000 + 200000 + 4;
  hipMemsetAsync(gnn, 0, zero_f * sizeof(float), stream);

  k_init<<<(N_NODES*DD + 255)/256, 256, 0, stream>>>(fu, fi, cur, total);

  for (int layer = 0; layer < 2; ++layer){
    if (layer) hipMemsetAsync(gnn, 0, (size_t)9600000 * sizeof(float), stream);
    k_spmm<<<(int)(((long)E_G*DD + 255)/256), 256, 0, stream>>>(G_idx, G_val, cur, gnn);
    k_intent<<<(N_USERS + 3)/4, 256, 0, stream>>>(u_int, gnn, cur, total, 0, N_USERS);
    k_intent<<<(N_ITEMS + 3)/4, 256, 0, stream>>>(i_int, gnn, cur, total, N_USERS, N_ITEMS);
  }

  // HAN degrees
  for (int m = 0; m < 2; ++m){
    const int* src = mp_u + (long)m*2*EU;
    k_deg<<<(EU + 255)/256, 256, 0, stream>>>(src, src + EU, EU,
        deg_u + m*N_USERS, deg_u + 2*N_USERS + m*N_USERS);
  }
  for (int m = 0; m < 2; ++m){
    const int* src = mp_i + (long)m*2*EI;
    k_deg<<<(EI + 255)/256, 256, 0, stream>>>(src, src + EI, EI,
        deg_i + m*N_ITEMS, deg_i + 2*N_ITEMS + m*N_ITEMS);
  }
  // HAN scatter (agg into z)
  for (int m = 0; m < 2; ++m){
    const int* src = mp_u + (long)m*2*EU;
    k_scatter<<<(int)(((long)EU*DD + 255)/256), 256, 0, stream>>>(src, src + EU, EU,
        fu, deg_u + m*N_USERS, z_u + (long)m*N_USERS*DD);
  }
  for (int m = 0; m < 2; ++m){
    const int* src = mp_i + (long)m*2*EI;
    k_scatter<<<(int)(((long)EI*DD + 255)/256), 256, 0, stream>>>(src, src + EI, EI,
        fi, deg_i + m*N_ITEMS, z_i + (long)m*N_ITEMS*DD);
  }
  // semantic attention reductions
  k_sem<<<(N_USERS + 3)/4, 256, 0, stream>>>(uW1, ub1, uw2, deg_u + 2*N_USERS, z_u, N_USERS, wsum);
  k_sem<<<(N_ITEMS + 3)/4, 256, 0, stream>>>(iW1, ib1, iw2, deg_i + 2*N_ITEMS, z_i, N_ITEMS, wsum + 2);
  k_beta<<<1, 64, 0, stream>>>(wsum, beta);
  k_final<<<(N_NODES*DD + 255)/256, 256, 0, stream>>>(total, z_u, z_i, beta, out);
}

// Round 4
// 3603.105 us; speedup vs baseline: 1.3348x; 1.3348x over previous
//
#include <hip/hip_runtime.h>
#include <hip/hip_bf16.h>
#include <math.h>

#define N_USERS 100000
#define N_ITEMS 50000
#define N_NODES 150000
#define DD 64
#define E_G 3200000
#define EU 1600000
#define EI 800000
#define E_HAN 4800000
#define NH 300000   // 100k + 100k + 50k + 50k concatenated HAN node space

__device__ __forceinline__ float invdeg(float d){
  return d > 0.f ? rsqrtf(fmaxf(d, 1e-12f)) : 0.f;
}

// cur = total = concat(feat_user, feat_item)
__global__ void k_init(const float* __restrict__ fu, const float* __restrict__ fi,
                       float* __restrict__ cur, float* __restrict__ total){
  int i = blockIdx.x*256 + threadIdx.x;
  if (i >= N_NODES*DD) return;
  float v = (i < N_USERS*DD) ? fu[i] : fi[i - N_USERS*DD];
  cur[i] = v; total[i] = v;
}

// ---------------- CSR build helpers ----------------
__global__ void k_hist(const int* __restrict__ idx, int ne, int* __restrict__ cnt){
  int e = blockIdx.x*256 + threadIdx.x;
  if (e >= ne) return;
  atomicAdd(&cnt[idx[e]], 1);
}

// block-local exclusive scan of cnt -> off (local), block sums -> bsum
__global__ void k_scan1(const int* __restrict__ cnt, int n,
                        int* __restrict__ off, int* __restrict__ bsum){
  __shared__ int s[256];
  int tid = threadIdx.x;
  int i = blockIdx.x*256 + tid;
  int v = (i < n) ? cnt[i] : 0;
  s[tid] = v; __syncthreads();
  for (int o = 1; o < 256; o <<= 1){
    int t = (tid >= o) ? s[tid - o] : 0;
    __syncthreads();
    s[tid] += t;
    __syncthreads();
  }
  if (i < n) off[i] = s[tid] - v;           // exclusive, block-local
  if (tid == 255) bsum[blockIdx.x] = s[255];
}

// single-block in-place exclusive scan over bsum[nb]
__global__ void k_scan2(int* __restrict__ bsum, int nb){
  __shared__ int s[256];
  __shared__ int carry;
  int tid = threadIdx.x;
  if (tid == 0) carry = 0;
  __syncthreads();
  for (int base = 0; base < nb; base += 256){
    int i = base + tid;
    int v = (i < nb) ? bsum[i] : 0;
    s[tid] = v; __syncthreads();
    for (int o = 1; o < 256; o <<= 1){
      int t = (tid >= o) ? s[tid - o] : 0;
      __syncthreads();
      s[tid] += t;
      __syncthreads();
    }
    int c = carry;
    if (i < nb) bsum[i] = c + s[tid] - v;   // exclusive
    __syncthreads();
    if (tid == 255) carry = c + s[255];
    __syncthreads();
  }
}

// off[i] += bsum[block]; cursor[i] = off[i]; off[n] = total
__global__ void k_scan3(int* __restrict__ off, const int* __restrict__ bsum,
                        int n, int total, int* __restrict__ cursor){
  int i = blockIdx.x*256 + threadIdx.x;
  if (i < n){
    int o = off[i] + bsum[blockIdx.x];
    off[i] = o; cursor[i] = o;
  }
  if (i == 0) off[n] = total;
}

// G edges: sorted-by-dst payload (src, val)
__global__ void k_gscatter(const int* __restrict__ gi, const float* __restrict__ gv,
                           int* __restrict__ cursor, int* __restrict__ ssrc,
                           float* __restrict__ sval){
  int e = blockIdx.x*256 + threadIdx.x;
  if (e >= E_G) return;
  int d = gi[e];
  int pos = atomicAdd(&cursor[d], 1);
  ssrc[pos] = gi[E_G + e];
  sval[pos] = gv[e];
}

// ---------------- DCCF: spmm gather + intent ----------------
__global__ __launch_bounds__(256) void k_spmm_g(const int* __restrict__ off,
        const int* __restrict__ ssrc, const float* __restrict__ sval,
        const float* __restrict__ cur, float* __restrict__ gnn){
  int wv = threadIdx.x >> 6, lane = threadIdx.x & 63;
  int node = blockIdx.x*4 + wv;
  if (node >= N_NODES) return;
  int b = off[node], e = off[node+1];
  float acc = 0.f;
  int k = b;
  for (; k + 1 < e; k += 2){
    int s0 = ssrc[k], s1 = ssrc[k+1];
    float v0 = sval[k], v1 = sval[k+1];
    acc += v0 * cur[s0*DD + lane];
    acc += v1 * cur[s1*DD + lane];
  }
  if (k < e) acc += sval[k] * cur[ssrc[k]*DD + lane];
  gnn[node*DD + lane] = acc;
}

__global__ __launch_bounds__(256) void k_intent(const float* __restrict__ intent,
        const float* __restrict__ gnn, float* __restrict__ cur, float* __restrict__ total,
        int base, int nrows){
  __shared__ float sInt[64*129];
  __shared__ float sP[4*128];
  int tid = threadIdx.x;
  for (int i = tid; i < 64*128; i += 256)
    sInt[(i>>7)*129 + (i&127)] = intent[i];
  __syncthreads();
  int wv = tid >> 6, lane = tid & 63;
  int r = blockIdx.x*4 + wv;
  bool valid = r < nrows;
  int row = base + (valid ? r : 0);
  float rv = cur[row*DD + lane];
  float w0 = 0.f, w1 = 0.f;
  for (int d = 0; d < 64; ++d){
    float rd = __shfl(rv, d, 64);
    w0 += rd * sInt[d*129 + lane];
    w1 += rd * sInt[d*129 + 64 + lane];
  }
  float mx = fmaxf(w0, w1);
  for (int off = 32; off; off >>= 1) mx = fmaxf(mx, __shfl_xor(mx, off, 64));
  float e0 = __expf(w0 - mx), e1 = __expf(w1 - mx);
  float s = e0 + e1;
  for (int off = 32; off; off >>= 1) s += __shfl_xor(s, off, 64);
  float inv_s = 1.f / s;
  sP[wv*128 + lane]      = e0 * inv_s;
  sP[wv*128 + 64 + lane] = e1 * inv_s;
  __syncthreads();
  float o = 0.f;
  for (int j = 0; j < 128; ++j)
    o += sP[wv*128 + j] * sInt[lane*129 + j];
  if (valid){
    float cn = gnn[row*DD + lane] + o + rv;
    cur[row*DD + lane] = cn;
    total[row*DD + lane] += cn;
  }
}

// ---------------- HAN ----------------
// concatenated node space: [0,100k)=u mp0, [100k,200k)=u mp1, [200k,250k)=i mp0, [250k,300k)=i mp1
__device__ __forceinline__ void han_decode(int t, const int* mp_u, const int* mp_i,
                                           const int** sp, const int** dp, int* e, int* nb){
  if (t < 2*EU){
    int s = (t < EU) ? 0 : 1;
    *e = t - s*EU;
    *sp = mp_u + (long)s*2*EU; *dp = *sp + EU;
    *nb = s*N_USERS;
  } else {
    int t2 = t - 2*EU;
    int s = (t2 < EI) ? 0 : 1;
    *e = t2 - s*EI;
    *sp = mp_i + (long)s*2*EI; *dp = *sp + EI;
    *nb = 2*N_USERS + s*N_ITEMS;
  }
}

__global__ void k_han_hist(const int* __restrict__ mp_u, const int* __restrict__ mp_i,
                           int* __restrict__ degout, int* __restrict__ cnt){
  int t = blockIdx.x*256 + threadIdx.x;
  if (t >= E_HAN) return;
  const int *sp, *dp; int e, nb;
  han_decode(t, mp_u, mp_i, &sp, &dp, &e, &nb);
  atomicAdd(&degout[nb + sp[e]], 1);
  atomicAdd(&cnt[nb + dp[e]], 1);
}

__global__ void k_hscatter(const int* __restrict__ mp_u, const int* __restrict__ mp_i,
                           int* __restrict__ cursor, int* __restrict__ ssrc){
  int t = blockIdx.x*256 + threadIdx.x;
  if (t >= E_HAN) return;
  const int *sp, *dp; int e, nb;
  han_decode(t, mp_u, mp_i, &sp, &dp, &e, &nb);
  int pos = atomicAdd(&cursor[nb + dp[e]], 1);
  ssrc[pos] = sp[e];                       // local src id
}

// z[g] = inv(deg_in[g]) * sum_e inv(deg_out[src]) * h[src]
__global__ __launch_bounds__(256) void k_han_g(const int* __restrict__ off,
        const int* __restrict__ ssrc, const int* __restrict__ degout,
        const int* __restrict__ cnt, const float* __restrict__ fu,
        const float* __restrict__ fi, float* __restrict__ z){
  int wv = threadIdx.x >> 6, lane = threadIdx.x & 63;
  int g = blockIdx.x*4 + wv;
  if (g >= NH) return;
  int nb = (g < N_USERS) ? 0 : (g < 2*N_USERS) ? N_USERS
         : (g < 2*N_USERS + N_ITEMS) ? 2*N_USERS : 2*N_USERS + N_ITEMS;
  const float* h = (g < 2*N_USERS) ? fu : fi;
  int b = off[g], e = off[g+1];
  float acc = 0.f;
  int k = b;
  for (; k + 1 < e; k += 2){
    int s0 = ssrc[k], s1 = ssrc[k+1];
    float w0 = invdeg((float)degout[nb + s0]);
    float w1 = invdeg((float)degout[nb + s1]);
    acc += w0 * h[s0*DD + lane];
    acc += w1 * h[s1*DD + lane];
  }
  if (k < e){
    int s0 = ssrc[k];
    acc += invdeg((float)degout[nb + s0]) * h[s0*DD + lane];
  }
  float win = invdeg((float)cnt[g]);
  z[g*DD + lane] = win * acc;
}

// w[n,m] = tanh(z[m,n]@W1 + b1)@w2 ; accumulate column sums into wsum[0..1]
__global__ __launch_bounds__(256) void k_sem(const float* __restrict__ W1, const float* __restrict__ b1,
        const float* __restrict__ w2, const float* __restrict__ z, int nn,
        float* __restrict__ wsum){
  __shared__ float sW[64*129];
  __shared__ float sB[128], sV[128];
  __shared__ float sAcc[8];
  int tid = threadIdx.x;
  for (int i = tid; i < 64*128; i += 256) sW[(i>>7)*129 + (i&127)] = W1[i];
  if (tid < 128){ sB[tid] = b1[tid]; sV[tid] = w2[tid]; }
  __syncthreads();
  int wv = tid >> 6, lane = tid & 63;
  int n = blockIdx.x*4 + wv;
  bool valid = n < nn;
  int nc = valid ? n : 0;
  float wm[2];
  for (int m = 0; m < 2; ++m){
    float zv = z[((long)m*nn + nc)*DD + lane];
    float t0 = sB[lane], t1 = sB[64 + lane];
    for (int d = 0; d < 64; ++d){
      float zd = __shfl(zv, d, 64);
      t0 += zd * sW[d*129 + lane];
      t1 += zd * sW[d*129 + 64 + lane];
    }
    float v = tanhf(t0)*sV[lane] + tanhf(t1)*sV[64 + lane];
    for (int off = 32; off; off >>= 1) v += __shfl_xor(v, off, 64);
    wm[m] = valid ? v : 0.f;
  }
  if (lane == 0){ sAcc[wv*2] = wm[0]; sAcc[wv*2 + 1] = wm[1]; }
  __syncthreads();
  if (tid == 0){
    atomicAdd(&wsum[0], sAcc[0] + sAcc[2] + sAcc[4] + sAcc[6]);
    atomicAdd(&wsum[1], sAcc[1] + sAcc[3] + sAcc[5] + sAcc[7]);
  }
}

__global__ void k_beta(const float* __restrict__ wsum, float* __restrict__ beta){
  if (threadIdx.x == 0 && blockIdx.x == 0){
    float u0 = wsum[0] / (float)N_USERS, u1 = wsum[1] / (float)N_USERS;
    float m = fmaxf(u0, u1);
    float e0 = __expf(u0 - m), e1 = __expf(u1 - m);
    beta[0] = e0/(e0+e1); beta[1] = e1/(e0+e1);
    float i0 = wsum[2] / (float)N_ITEMS, i1 = wsum[3] / (float)N_ITEMS;
    m = fmaxf(i0, i1);
    e0 = __expf(i0 - m); e1 = __expf(i1 - m);
    beta[2] = e0/(e0+e1); beta[3] = e1/(e0+e1);
  }
}

__global__ void k_final(const float* __restrict__ total, const float* __restrict__ z_all,
                        const float* __restrict__ beta, float* __restrict__ out){
  int i = blockIdx.x*256 + threadIdx.x;
  if (i >= N_NODES*DD) return;
  float h;
  if (i < N_USERS*DD) h = beta[0]*z_all[i] + beta[1]*z_all[N_USERS*DD + i];
  else {
    int j = i - N_USERS*DD;
    h = beta[2]*z_all[2*N_USERS*DD + j] + beta[3]*z_all[(2*N_USERS + N_ITEMS)*DD + j];
  }
  out[i] = 0.5f*total[i] + 0.5f*h;
}

extern "C" void kernel_launch(void* const* d_in, const int* in_sizes, int n_in,
                              void* d_out, int out_size, void* d_ws, size_t ws_size,
                              hipStream_t stream) {
  const int*   G_idx = (const int*)d_in[0];
  const float* G_val = (const float*)d_in[1];
  const float* fu    = (const float*)d_in[2];
  const float* fi    = (const float*)d_in[3];
  const float* u_int = (const float*)d_in[4];
  const float* i_int = (const float*)d_in[5];
  const int*   mp_u  = (const int*)d_in[6];
  const int*   mp_i  = (const int*)d_in[7];
  const float* uW1   = (const float*)d_in[8];
  const float* ub1   = (const float*)d_in[9];
  const float* uw2   = (const float*)d_in[10];
  const float* iW1   = (const float*)d_in[11];
  const float* ib1   = (const float*)d_in[12];
  const float* iw2   = (const float*)d_in[13];
  float* out = (float*)d_out;

  // workspace layout (4-byte element offsets); phases alias:
  //   phase A (layers): total, cur, gnn, G-CSR
  //   phase B (HAN):    total, z_all (over cur+gnn), HAN-CSR (over G-CSR)
  float* ws    = (float*)d_ws;
  float* total = ws;                          // 9.6M f
  float* cur   = ws + 9600000;                // 9.6M f     [phase A]
  float* gnn   = ws + 19200000;               // 9.6M f     [phase A]
  float* z_all = ws + 9600000;                // 19.2M f    [phase B, aliases cur+gnn]
  // G CSR slab @ 28.8M
  int*   ssrcG = (int*)(ws + 28800000);       // 3.2M i
  float* svalG = ws + 32000000;               // 3.2M f
  int*   cntG  = (int*)(ws + 35200000);       // 150k i
  int*   offG  = (int*)(ws + 35350000);       // 150001 i
  int*   curG  = (int*)(ws + 35500004);       // 150k i
  // HAN slab @ 28.8M (aliases G CSR; used only after layers)
  int*   ssrcH = (int*)(ws + 28800000);       // 4.8M i
  int*   degoH = (int*)(ws + 33600000);       // 300k i
  int*   cntH  = (int*)(ws + 33900000);       // 300k i
  int*   offH  = (int*)(ws + 34200000);       // 300004 i
  int*   curH  = (int*)(ws + 34500004);       // 300k i
  // smalls @ 36.0M (outside both slabs)
  int*   bsum  = (int*)(ws + 36000000);       // up to 1172 i
  float* wsum  = ws + 36002000;               // 4 f
  float* beta  = ws + 36002004;               // 4 f

  hipMemsetAsync(cntG, 0, (size_t)N_NODES*sizeof(int), stream);
  hipMemsetAsync(wsum, 0, 4*sizeof(float), stream);

  k_init<<<(N_NODES*DD + 255)/256, 256, 0, stream>>>(fu, fi, cur, total);

  // ---- G CSR build (by dst = G_idx row 0) ----
  {
    int nbk = (N_NODES + 255)/256;  // 586
    k_hist<<<(E_G + 255)/256, 256, 0, stream>>>(G_idx, E_G, cntG);
    k_scan1<<<nbk, 256, 0, stream>>>(cntG, N_NODES, offG, bsum);
    k_scan2<<<1, 256, 0, stream>>>(bsum, nbk);
    k_scan3<<<nbk, 256, 0, stream>>>(offG, bsum, N_NODES, E_G, curG);
    k_gscatter<<<(E_G + 255)/256, 256, 0, stream>>>(G_idx, G_val, curG, ssrcG, svalG);
  }

  // ---- DCCF layers ----
  for (int layer = 0; layer < 2; ++layer){
    k_spmm_g<<<(N_NODES + 3)/4, 256, 0, stream>>>(offG, ssrcG, svalG, cur, gnn);
    k_intent<<<(N_USERS + 3)/4, 256, 0, stream>>>(u_int, gnn, cur, total, 0, N_USERS);
    k_intent<<<(N_ITEMS + 3)/4, 256, 0, stream>>>(i_int, gnn, cur, total, N_USERS, N_ITEMS);
  }

  // ---- HAN CSR build + gather (aliased slabs: only after layers) ----
  {
    hipMemsetAsync(degoH, 0, (size_t)2*NH*sizeof(int), stream);  // degoH+cntH contiguous
    int nbk = (NH + 255)/256;  // 1172
    k_han_hist<<<(E_HAN + 255)/256, 256, 0, stream>>>(mp_u, mp_i, degoH, cntH);
    k_scan1<<<nbk, 256, 0, stream>>>(cntH, NH, offH, bsum);
    k_scan2<<<1, 256, 0, stream>>>(bsum, nbk);
    k_scan3<<<nbk, 256, 0, stream>>>(offH, bsum, NH, E_HAN, curH);
    k_hscatter<<<(E_HAN + 255)/256, 256, 0, stream>>>(mp_u, mp_i, curH, ssrcH);
    k_han_g<<<(NH + 3)/4, 256, 0, stream>>>(offH, ssrcH, degoH, cntH, fu, fi, z_all);
  }

  // ---- semantic attention + combine ----
  k_sem<<<(N_USERS + 3)/4, 256, 0, stream>>>(uW1, ub1, uw2, z_all, N_USERS, wsum);
  k_sem<<<(N_ITEMS + 3)/4, 256, 0, stream>>>(iW1, ib1, iw2, z_all + (long)2*N_USERS*DD, N_ITEMS, wsum + 2);
  k_beta<<<1, 64, 0, stream>>>(wsum, beta);
  k_final<<<(N_NODES*DD + 255)/256, 256, 0, stream>>>(total, z_all, beta, out);
}

// Round 5
// 2215.162 us; speedup vs baseline: 2.1712x; 1.6266x over previous
//
#include <hip/hip_runtime.h>
#include <hip/hip_bf16.h>
#include <math.h>

#define N_USERS 100000
#define N_ITEMS 50000
#define N_NODES 150000
#define DD 64
#define E_G 3200000
#define EU 1600000
#define EI 800000
#define E_HAN 4800000
#define NH 300000   // 100k + 100k + 50k + 50k concatenated HAN node space
#define ROWS 32

__device__ __forceinline__ float invdeg(float d){
  return d > 0.f ? rsqrtf(fmaxf(d, 1e-12f)) : 0.f;
}

__device__ __forceinline__ float tanh_fast(float x){
  float cx = fminf(15.f, fmaxf(-15.f, x));
  float t = __expf(2.f*cx);
  return (t - 1.f)/(t + 1.f);
}

// cur = total = concat(feat_user, feat_item)
__global__ void k_init(const float* __restrict__ fu, const float* __restrict__ fi,
                       float* __restrict__ cur, float* __restrict__ total){
  int i = blockIdx.x*256 + threadIdx.x;
  if (i >= N_NODES*DD) return;
  float v = (i < N_USERS*DD) ? fu[i] : fi[i - N_USERS*DD];
  cur[i] = v; total[i] = v;
}

// ---------------- CSR build helpers ----------------
__global__ void k_hist(const int* __restrict__ idx, int ne, int* __restrict__ cnt){
  int e = blockIdx.x*256 + threadIdx.x;
  if (e >= ne) return;
  atomicAdd(&cnt[idx[e]], 1);
}

__global__ void k_scan1(const int* __restrict__ cnt, int n,
                        int* __restrict__ off, int* __restrict__ bsum){
  __shared__ int s[256];
  int tid = threadIdx.x;
  int i = blockIdx.x*256 + tid;
  int v = (i < n) ? cnt[i] : 0;
  s[tid] = v; __syncthreads();
  for (int o = 1; o < 256; o <<= 1){
    int t = (tid >= o) ? s[tid - o] : 0;
    __syncthreads();
    s[tid] += t;
    __syncthreads();
  }
  if (i < n) off[i] = s[tid] - v;
  if (tid == 255) bsum[blockIdx.x] = s[255];
}

__global__ void k_scan2(int* __restrict__ bsum, int nb){
  __shared__ int s[256];
  __shared__ int carry;
  int tid = threadIdx.x;
  if (tid == 0) carry = 0;
  __syncthreads();
  for (int base = 0; base < nb; base += 256){
    int i = base + tid;
    int v = (i < nb) ? bsum[i] : 0;
    s[tid] = v; __syncthreads();
    for (int o = 1; o < 256; o <<= 1){
      int t = (tid >= o) ? s[tid - o] : 0;
      __syncthreads();
      s[tid] += t;
      __syncthreads();
    }
    int c = carry;
    if (i < nb) bsum[i] = c + s[tid] - v;
    __syncthreads();
    if (tid == 255) carry = c + s[255];
    __syncthreads();
  }
}

__global__ void k_scan3(int* __restrict__ off, const int* __restrict__ bsum,
                        int n, int total, int* __restrict__ cursor){
  int i = blockIdx.x*256 + threadIdx.x;
  if (i < n){
    int o = off[i] + bsum[blockIdx.x];
    off[i] = o; cursor[i] = o;
  }
  if (i == 0) off[n] = total;
}

__global__ void k_gscatter(const int* __restrict__ gi, const float* __restrict__ gv,
                           int* __restrict__ cursor, int* __restrict__ ssrc,
                           float* __restrict__ sval){
  int e = blockIdx.x*256 + threadIdx.x;
  if (e >= E_G) return;
  int d = gi[e];
  int pos = atomicAdd(&cursor[d], 1);
  ssrc[pos] = gi[E_G + e];
  sval[pos] = gv[e];
}

// ---------------- DCCF: spmm gather (4 edges/iter, float4 lanes) ----------------
__global__ __launch_bounds__(256) void k_spmm_g4(const int* __restrict__ off,
        const int* __restrict__ ssrc, const float* __restrict__ sval,
        const float* __restrict__ cur, float* __restrict__ gnn){
  int wv = threadIdx.x >> 6, lane = threadIdx.x & 63;
  int node = blockIdx.x*4 + wv;
  if (node >= N_NODES) return;
  int b = off[node], e = off[node+1];
  int c4 = (lane & 15)*4, sl = lane >> 4;
  float ax=0.f, ay=0.f, az=0.f, aw=0.f;
  for (int k = b; k < e; k += 4){
    int idx = k + sl;
    bool v = idx < e;
    int s = v ? ssrc[idx] : 0;
    float val = v ? sval[idx] : 0.f;
    const float4 x = *(const float4*)&cur[s*DD + c4];
    ax += val*x.x; ay += val*x.y; az += val*x.z; aw += val*x.w;
  }
  ax += __shfl_xor(ax, 16, 64); ay += __shfl_xor(ay, 16, 64);
  az += __shfl_xor(az, 16, 64); aw += __shfl_xor(aw, 16, 64);
  ax += __shfl_xor(ax, 32, 64); ay += __shfl_xor(ay, 32, 64);
  az += __shfl_xor(az, 32, 64); aw += __shfl_xor(aw, 32, 64);
  if (lane < 16) *(float4*)&gnn[node*DD + c4] = make_float4(ax, ay, az, aw);
}

// ---------------- intent: tiled GEMM + softmax + GEMM ----------------
__global__ __launch_bounds__(256) void k_intent2(const float* __restrict__ intent,
        const float* __restrict__ gnn, float* __restrict__ cur, float* __restrict__ total,
        int base, int nrows){
  __shared__ float sB[64*132];   // intent [d][c] row-major, stride 132
  __shared__ float sU[ROWS*132]; // union: sAT[d][r] stride 36 (phase1) / sP[r][j] stride 132 (phase2)
  int tid = threadIdx.x, tx = tid & 15, ty = tid >> 4;

  for (int i = tid; i < 2048; i += 256){
    int r = i >> 5, c = (i & 31) << 2;
    *(float4*)&sB[r*132 + c] = *(const float4*)&intent[r*128 + c];
  }
  {
    int r = tid & 31, q0 = tid >> 5;
    int rr = blockIdx.x*ROWS + r;
    int rowg = base + (rr < nrows ? rr : nrows - 1);
    for (int q = q0; q < 16; q += 8){
      float4 v = *(const float4*)&cur[rowg*DD + 4*q];
      sU[(4*q+0)*36 + r] = v.x;
      sU[(4*q+1)*36 + r] = v.y;
      sU[(4*q+2)*36 + r] = v.z;
      sU[(4*q+3)*36 + r] = v.w;
    }
  }
  __syncthreads();

  // phase 1: w[2][8] = A(2 rows) @ B(cols 8tx..8tx+7)
  float w[2][8];
  #pragma unroll
  for (int i = 0; i < 2; ++i)
    #pragma unroll
    for (int k = 0; k < 8; ++k) w[i][k] = 0.f;
  for (int d = 0; d < 64; ++d){
    float2 a = *(const float2*)&sU[d*36 + 2*ty];
    float4 b0 = *(const float4*)&sB[d*132 + 8*tx];
    float4 b1 = *(const float4*)&sB[d*132 + 8*tx + 4];
    float bb[8] = {b0.x,b0.y,b0.z,b0.w,b1.x,b1.y,b1.z,b1.w};
    #pragma unroll
    for (int k = 0; k < 8; ++k){ w[0][k] += a.x*bb[k]; w[1][k] += a.y*bb[k]; }
  }

  // softmax per row over 128 cols (16 lanes x 8)
  float p[2][8];
  #pragma unroll
  for (int i = 0; i < 2; ++i){
    float mx = w[i][0];
    #pragma unroll
    for (int k = 1; k < 8; ++k) mx = fmaxf(mx, w[i][k]);
    mx = fmaxf(mx, __shfl_xor(mx, 1, 64));
    mx = fmaxf(mx, __shfl_xor(mx, 2, 64));
    mx = fmaxf(mx, __shfl_xor(mx, 4, 64));
    mx = fmaxf(mx, __shfl_xor(mx, 8, 64));
    float s = 0.f;
    #pragma unroll
    for (int k = 0; k < 8; ++k){ p[i][k] = __expf(w[i][k] - mx); s += p[i][k]; }
    s += __shfl_xor(s, 1, 64);
    s += __shfl_xor(s, 2, 64);
    s += __shfl_xor(s, 4, 64);
    s += __shfl_xor(s, 8, 64);
    float inv = 1.f / s;
    #pragma unroll
    for (int k = 0; k < 8; ++k) p[i][k] *= inv;
  }
  __syncthreads();  // done reading sAT
  #pragma unroll
  for (int i = 0; i < 2; ++i){
    *(float4*)&sU[(2*ty+i)*132 + 8*tx]     = make_float4(p[i][0],p[i][1],p[i][2],p[i][3]);
    *(float4*)&sU[(2*ty+i)*132 + 8*tx + 4] = make_float4(p[i][4],p[i][5],p[i][6],p[i][7]);
  }
  __syncthreads();

  // phase 2: o[2][4] = P(2 rows x 128) @ intent^T (cols l = 4tx..4tx+3)
  float o[2][4];
  #pragma unroll
  for (int i = 0; i < 2; ++i)
    #pragma unroll
    for (int m = 0; m < 4; ++m) o[i][m] = 0.f;
  for (int q = 0; q < 32; ++q){
    float4 p0 = *(const float4*)&sU[(2*ty+0)*132 + 4*q];
    float4 p1 = *(const float4*)&sU[(2*ty+1)*132 + 4*q];
    #pragma unroll
    for (int m = 0; m < 4; ++m){
      float4 bl = *(const float4*)&sB[(4*tx+m)*132 + 4*q];
      o[0][m] += p0.x*bl.x + p0.y*bl.y + p0.z*bl.z + p0.w*bl.w;
      o[1][m] += p1.x*bl.x + p1.y*bl.y + p1.z*bl.z + p1.w*bl.w;
    }
  }

  #pragma unroll
  for (int i = 0; i < 2; ++i){
    int rr = blockIdx.x*ROWS + 2*ty + i;
    if (rr < nrows){
      int rowg = base + rr;
      float4 g = *(const float4*)&gnn[rowg*DD + 4*tx];
      float4 c = *(const float4*)&cur[rowg*DD + 4*tx];
      float4 t = *(const float4*)&total[rowg*DD + 4*tx];
      float4 cn = make_float4(g.x + o[i][0] + c.x, g.y + o[i][1] + c.y,
                              g.z + o[i][2] + c.z, g.w + o[i][3] + c.w);
      *(float4*)&cur[rowg*DD + 4*tx] = cn;
      *(float4*)&total[rowg*DD + 4*tx] =
          make_float4(t.x + cn.x, t.y + cn.y, t.z + cn.z, t.w + cn.w);
    }
  }
}

// ---------------- HAN ----------------
__device__ __forceinline__ void han_decode(int t, const int* mp_u, const int* mp_i,
                                           const int** sp, const int** dp, int* e, int* nb){
  if (t < 2*EU){
    int s = (t < EU) ? 0 : 1;
    *e = t - s*EU;
    *sp = mp_u + (long)s*2*EU; *dp = *sp + EU;
    *nb = s*N_USERS;
  } else {
    int t2 = t - 2*EU;
    int s = (t2 < EI) ? 0 : 1;
    *e = t2 - s*EI;
    *sp = mp_i + (long)s*2*EI; *dp = *sp + EI;
    *nb = 2*N_USERS + s*N_ITEMS;
  }
}

__global__ void k_han_hist(const int* __restrict__ mp_u, const int* __restrict__ mp_i,
                           int* __restrict__ degout, int* __restrict__ cnt){
  int t = blockIdx.x*256 + threadIdx.x;
  if (t >= E_HAN) return;
  const int *sp, *dp; int e, nb;
  han_decode(t, mp_u, mp_i, &sp, &dp, &e, &nb);
  atomicAdd(&degout[nb + sp[e]], 1);
  atomicAdd(&cnt[nb + dp[e]], 1);
}

__global__ void k_hscatter(const int* __restrict__ mp_u, const int* __restrict__ mp_i,
                           int* __restrict__ cursor, int* __restrict__ ssrc){
  int t = blockIdx.x*256 + threadIdx.x;
  if (t >= E_HAN) return;
  const int *sp, *dp; int e, nb;
  han_decode(t, mp_u, mp_i, &sp, &dp, &e, &nb);
  int pos = atomicAdd(&cursor[nb + dp[e]], 1);
  ssrc[pos] = sp[e];
}

__global__ __launch_bounds__(256) void k_han_g4(const int* __restrict__ off,
        const int* __restrict__ ssrc, const int* __restrict__ degout,
        const int* __restrict__ cnt, const float* __restrict__ fu,
        const float* __restrict__ fi, float* __restrict__ z){
  int wv = threadIdx.x >> 6, lane = threadIdx.x & 63;
  int g = blockIdx.x*4 + wv;
  if (g >= NH) return;
  int nb = (g < N_USERS) ? 0 : (g < 2*N_USERS) ? N_USERS
         : (g < 2*N_USERS + N_ITEMS) ? 2*N_USERS : 2*N_USERS + N_ITEMS;
  const float* h = (g < 2*N_USERS) ? fu : fi;
  int b = off[g], e = off[g+1];
  int c4 = (lane & 15)*4, sl = lane >> 4;
  float ax=0.f, ay=0.f, az=0.f, aw=0.f;
  for (int k = b; k < e; k += 4){
    int idx = k + sl;
    bool v = idx < e;
    int s = v ? ssrc[idx] : 0;
    float wgt = v ? invdeg((float)degout[nb + s]) : 0.f;
    const float4 x = *(const float4*)&h[s*DD + c4];
    ax += wgt*x.x; ay += wgt*x.y; az += wgt*x.z; aw += wgt*x.w;
  }
  ax += __shfl_xor(ax, 16, 64); ay += __shfl_xor(ay, 16, 64);
  az += __shfl_xor(az, 16, 64); aw += __shfl_xor(aw, 16, 64);
  ax += __shfl_xor(ax, 32, 64); ay += __shfl_xor(ay, 32, 64);
  az += __shfl_xor(az, 32, 64); aw += __shfl_xor(aw, 32, 64);
  if (lane < 16){
    float win = invdeg((float)cnt[g]);
    *(float4*)&z[g*DD + c4] = make_float4(win*ax, win*ay, win*az, win*aw);
  }
}

// ---------------- semantic attention reduction ----------------
__global__ __launch_bounds__(256) void k_sem2(const float* __restrict__ W1,
        const float* __restrict__ b1, const float* __restrict__ w2,
        const float* __restrict__ z, int nn, float* __restrict__ wsum){
  __shared__ float sW[64*132];
  __shared__ float sA[64*36];
  __shared__ float sBias[128], sV[128];
  __shared__ float red[2];
  int tid = threadIdx.x, tx = tid & 15, ty = tid >> 4;

  for (int i = tid; i < 2048; i += 256){
    int r = i >> 5, c = (i & 31) << 2;
    *(float4*)&sW[r*132 + c] = *(const float4*)&W1[r*128 + c];
  }
  if (tid < 128){ sBias[tid] = b1[tid]; sV[tid] = w2[tid]; }
  if (tid < 2) red[tid] = 0.f;

  for (int m = 0; m < 2; ++m){
    __syncthreads();
    {
      int r = tid & 31, q0 = tid >> 5;
      int rr = blockIdx.x*ROWS + r;
      int rowg = (rr < nn ? rr : nn - 1) + m*nn;
      for (int q = q0; q < 16; q += 8){
        float4 v = *(const float4*)&z[(long)rowg*DD + 4*q];
        sA[(4*q+0)*36 + r] = v.x;
        sA[(4*q+1)*36 + r] = v.y;
        sA[(4*q+2)*36 + r] = v.z;
        sA[(4*q+3)*36 + r] = v.w;
      }
    }
    __syncthreads();

    float w[2][8];
    #pragma unroll
    for (int i = 0; i < 2; ++i)
      #pragma unroll
      for (int k = 0; k < 8; ++k) w[i][k] = sBias[8*tx + k];
    for (int d = 0; d < 64; ++d){
      float2 a = *(const float2*)&sA[d*36 + 2*ty];
      float4 b0 = *(const float4*)&sW[d*132 + 8*tx];
      float4 b4 = *(const float4*)&sW[d*132 + 8*tx + 4];
      float bb[8] = {b0.x,b0.y,b0.z,b0.w,b4.x,b4.y,b4.z,b4.w};
      #pragma unroll
      for (int k = 0; k < 8; ++k){ w[0][k] += a.x*bb[k]; w[1][k] += a.y*bb[k]; }
    }
    float part = 0.f;
    #pragma unroll
    for (int i = 0; i < 2; ++i){
      int rr = blockIdx.x*ROWS + 2*ty + i;
      if (rr < nn){
        #pragma unroll
        for (int k = 0; k < 8; ++k) part += tanh_fast(w[i][k]) * sV[8*tx + k];
      }
    }
    part += __shfl_xor(part, 1, 64);
    part += __shfl_xor(part, 2, 64);
    part += __shfl_xor(part, 4, 64);
    part += __shfl_xor(part, 8, 64);
    part += __shfl_xor(part, 16, 64);
    part += __shfl_xor(part, 32, 64);
    if ((tid & 63) == 0) atomicAdd(&red[m], part);
  }
  __syncthreads();
  if (tid < 2) atomicAdd(&wsum[tid], red[tid]);
}

__global__ void k_beta(const float* __restrict__ wsum, float* __restrict__ beta){
  if (threadIdx.x == 0 && blockIdx.x == 0){
    float u0 = wsum[0] / (float)N_USERS, u1 = wsum[1] / (float)N_USERS;
    float m = fmaxf(u0, u1);
    float e0 = __expf(u0 - m), e1 = __expf(u1 - m);
    beta[0] = e0/(e0+e1); beta[1] = e1/(e0+e1);
    float i0 = wsum[2] / (float)N_ITEMS, i1 = wsum[3] / (float)N_ITEMS;
    m = fmaxf(i0, i1);
    e0 = __expf(i0 - m); e1 = __expf(i1 - m);
    beta[2] = e0/(e0+e1); beta[3] = e1/(e0+e1);
  }
}

__global__ void k_final(const float* __restrict__ total, const float* __restrict__ z_all,
                        const float* __restrict__ beta, float* __restrict__ out){
  int i = blockIdx.x*256 + threadIdx.x;
  if (i >= N_NODES*DD) return;
  float h;
  if (i < N_USERS*DD) h = beta[0]*z_all[i] + beta[1]*z_all[N_USERS*DD + i];
  else {
    int j = i - N_USERS*DD;
    h = beta[2]*z_all[2*N_USERS*DD + j] + beta[3]*z_all[(2*N_USERS + N_ITEMS)*DD + j];
  }
  out[i] = 0.5f*total[i] + 0.5f*h;
}

extern "C" void kernel_launch(void* const* d_in, const int* in_sizes, int n_in,
                              void* d_out, int out_size, void* d_ws, size_t ws_size,
                              hipStream_t stream) {
  const int*   G_idx = (const int*)d_in[0];
  const float* G_val = (const float*)d_in[1];
  const float* fu    = (const float*)d_in[2];
  const float* fi    = (const float*)d_in[3];
  const float* u_int = (const float*)d_in[4];
  const float* i_int = (const float*)d_in[5];
  const int*   mp_u  = (const int*)d_in[6];
  const int*   mp_i  = (const int*)d_in[7];
  const float* uW1   = (const float*)d_in[8];
  const float* ub1   = (const float*)d_in[9];
  const float* uw2   = (const float*)d_in[10];
  const float* iW1   = (const float*)d_in[11];
  const float* ib1   = (const float*)d_in[12];
  const float* iw2   = (const float*)d_in[13];
  float* out = (float*)d_out;

  float* ws    = (float*)d_ws;
  float* total = ws;                          // 9.6M f
  float* cur   = ws + 9600000;                // 9.6M f     [phase A]
  float* gnn   = ws + 19200000;               // 9.6M f     [phase A]
  float* z_all = ws + 9600000;                // 19.2M f    [phase B, aliases cur+gnn]
  int*   ssrcG = (int*)(ws + 28800000);       // 3.2M i
  float* svalG = ws + 32000000;               // 3.2M f
  int*   cntG  = (int*)(ws + 35200000);       // 150k i
  int*   offG  = (int*)(ws + 35350000);       // 150001 i
  int*   curG  = (int*)(ws + 35500004);       // 150k i
  int*   ssrcH = (int*)(ws + 28800000);       // 4.8M i [aliases G CSR]
  int*   degoH = (int*)(ws + 33600000);       // 300k i
  int*   cntH  = (int*)(ws + 33900000);       // 300k i
  int*   offH  = (int*)(ws + 34200000);       // 300004 i
  int*   curH  = (int*)(ws + 34500004);       // 300k i
  int*   bsum  = (int*)(ws + 36000000);       // up to 1172 i
  float* wsum  = ws + 36002000;               // 4 f
  float* beta  = ws + 36002004;               // 4 f

  hipMemsetAsync(cntG, 0, (size_t)N_NODES*sizeof(int), stream);
  hipMemsetAsync(wsum, 0, 4*sizeof(float), stream);

  k_init<<<(N_NODES*DD + 255)/256, 256, 0, stream>>>(fu, fi, cur, total);

  // ---- G CSR build (by dst = G_idx row 0) ----
  {
    int nbk = (N_NODES + 255)/256;
    k_hist<<<(E_G + 255)/256, 256, 0, stream>>>(G_idx, E_G, cntG);
    k_scan1<<<nbk, 256, 0, stream>>>(cntG, N_NODES, offG, bsum);
    k_scan2<<<1, 256, 0, stream>>>(bsum, nbk);
    k_scan3<<<nbk, 256, 0, stream>>>(offG, bsum, N_NODES, E_G, curG);
    k_gscatter<<<(E_G + 255)/256, 256, 0, stream>>>(G_idx, G_val, curG, ssrcG, svalG);
  }

  // ---- DCCF layers ----
  for (int layer = 0; layer < 2; ++layer){
    k_spmm_g4<<<(N_NODES + 3)/4, 256, 0, stream>>>(offG, ssrcG, svalG, cur, gnn);
    k_intent2<<<(N_USERS + ROWS-1)/ROWS, 256, 0, stream>>>(u_int, gnn, cur, total, 0, N_USERS);
    k_intent2<<<(N_ITEMS + ROWS-1)/ROWS, 256, 0, stream>>>(i_int, gnn, cur, total, N_USERS, N_ITEMS);
  }

  // ---- HAN CSR build + gather ----
  {
    hipMemsetAsync(degoH, 0, (size_t)2*NH*sizeof(int), stream);
    int nbk = (NH + 255)/256;
    k_han_hist<<<(E_HAN + 255)/256, 256, 0, stream>>>(mp_u, mp_i, degoH, cntH);
    k_scan1<<<nbk, 256, 0, stream>>>(cntH, NH, offH, bsum);
    k_scan2<<<1, 256, 0, stream>>>(bsum, nbk);
    k_scan3<<<nbk, 256, 0, stream>>>(offH, bsum, NH, E_HAN, curH);
    k_hscatter<<<(E_HAN + 255)/256, 256, 0, stream>>>(mp_u, mp_i, curH, ssrcH);
    k_han_g4<<<(NH + 3)/4, 256, 0, stream>>>(offH, ssrcH, degoH, cntH, fu, fi, z_all);
  }

  // ---- semantic attention + combine ----
  k_sem2<<<(N_USERS + ROWS-1)/ROWS, 256, 0, stream>>>(uW1, ub1, uw2, z_all, N_USERS, wsum);
  k_sem2<<<(N_ITEMS + ROWS-1)/ROWS, 256, 0, stream>>>(iW1, ib1, iw2,
      z_all + (long)2*N_USERS*DD, N_ITEMS, wsum + 2);
  k_beta<<<1, 64, 0, stream>>>(wsum, beta);
  k_final<<<(N_NODES*DD + 255)/256, 256, 0, stream>>>(total, z_all, beta, out);
}

// Round 6
// 1803.898 us; speedup vs baseline: 2.6662x; 1.2280x over previous
//
#include <hip/hip_runtime.h>
#include <hip/hip_bf16.h>
#include <math.h>

#define N_USERS 100000
#define N_ITEMS 50000
#define N_NODES 150000
#define DD 64
#define E_G 3200000
#define EU 1600000
#define EI 800000
#define E_HAN 4800000
#define NH 300000
#define NBG 293        // ceil(150000/512)
#define NBH 586        // ceil(300000/512)
#define ROWS 32

__device__ __forceinline__ float invdeg(float d){
  return d > 0.f ? rsqrtf(fmaxf(d, 1e-12f)) : 0.f;
}
__device__ __forceinline__ float tanh_fast(float x){
  float cx = fminf(15.f, fmaxf(-15.f, x));
  float t = __expf(2.f*cx);
  return (t - 1.f)/(t + 1.f);
}
__device__ __forceinline__ unsigned short f2b(float x){
  unsigned int b = __float_as_uint(x);
  b += 0x7FFFu + ((b >> 16) & 1u);
  return (unsigned short)(b >> 16);
}
__device__ __forceinline__ float b2f(unsigned short u){
  return __uint_as_float(((unsigned int)u) << 16);
}

__global__ void k_init(const float* __restrict__ fu, const float* __restrict__ fi,
                       float* __restrict__ cur, float* __restrict__ total){
  int i = blockIdx.x*256 + threadIdx.x;
  if (i >= N_NODES*DD) return;
  float v = (i < N_USERS*DD) ? fu[i] : fi[i - N_USERS*DD];
  cur[i] = v; total[i] = v;
}

// ---------------- histogram / scan ----------------
__global__ void k_hist(const int* __restrict__ idx, int ne, int* __restrict__ cnt){
  int e = blockIdx.x*256 + threadIdx.x;
  if (e >= ne) return;
  atomicAdd(&cnt[idx[e]], 1);
}

__global__ void k_scan1(const int* __restrict__ cnt, int n,
                        int* __restrict__ off, int* __restrict__ bsum){
  __shared__ int s[256];
  int tid = threadIdx.x;
  int i = blockIdx.x*256 + tid;
  int v = (i < n) ? cnt[i] : 0;
  s[tid] = v; __syncthreads();
  for (int o = 1; o < 256; o <<= 1){
    int t = (tid >= o) ? s[tid - o] : 0;
    __syncthreads();
    s[tid] += t;
    __syncthreads();
  }
  if (i < n) off[i] = s[tid] - v;
  if (tid == 255) bsum[blockIdx.x] = s[255];
}

__global__ void k_scan2(int* __restrict__ bsum, int nb){
  __shared__ int s[256];
  __shared__ int carry;
  int tid = threadIdx.x;
  if (tid == 0) carry = 0;
  __syncthreads();
  for (int base = 0; base < nb; base += 256){
    int i = base + tid;
    int v = (i < nb) ? bsum[i] : 0;
    s[tid] = v; __syncthreads();
    for (int o = 1; o < 256; o <<= 1){
      int t = (tid >= o) ? s[tid - o] : 0;
      __syncthreads();
      s[tid] += t;
      __syncthreads();
    }
    int c = carry;
    if (i < nb) bsum[i] = c + s[tid] - v;
    __syncthreads();
    if (tid == 255) carry = c + s[255];
    __syncthreads();
  }
}

__global__ void k_scan3(int* __restrict__ off, const int* __restrict__ bsum,
                        int n, int total){
  int i = blockIdx.x*256 + threadIdx.x;
  if (i < n) off[i] += bsum[blockIdx.x];
  if (i == 0) off[n] = total;
}

__global__ void k_binit(int* __restrict__ bcur, const int* __restrict__ off, int nb){
  int b = blockIdx.x*256 + threadIdx.x;
  if (b < nb) bcur[b] = off[b*512];
}

// ---------------- G partition: phase 1 (dense bucketed records) ----------------
__global__ __launch_bounds__(256) void k_part1_g(const int* __restrict__ gi,
        const float* __restrict__ gv, int* __restrict__ bcur,
        unsigned int* __restrict__ key, float* __restrict__ val){
  __shared__ int hist[NBG];
  __shared__ int lcur[NBG];
  int tid = threadIdx.x;
  const int CH = E_G/256;            // 12500
  int e0 = blockIdx.x*CH;
  for (int b = tid; b < NBG; b += 256) hist[b] = 0;
  __syncthreads();
  for (int i = tid; i < CH; i += 256){
    int d = gi[e0 + i];
    atomicAdd(&hist[d >> 9], 1);
  }
  __syncthreads();
  for (int b = tid; b < NBG; b += 256)
    lcur[b] = atomicAdd(&bcur[b], hist[b]);
  __syncthreads();
  for (int i = tid; i < CH; i += 256){
    int e = e0 + i;
    int d = gi[e], s = gi[E_G + e];
    int p = atomicAdd(&lcur[d >> 9], 1);
    key[p] = ((unsigned int)(d & 511) << 18) | (unsigned int)s;
    val[p] = gv[e];
  }
}

// ---------------- G partition: phase 2 (exact CSR position, packed payload) ----
__global__ __launch_bounds__(256) void k_part2_g(const int* __restrict__ off,
        const unsigned int* __restrict__ key, const float* __restrict__ val,
        unsigned int* __restrict__ packed){
  __shared__ int lcur[512];
  int b = blockIdx.x, tid = threadIdx.x;
  int d0 = b*512;
  int dcnt = min(512, N_NODES - d0);
  for (int i = tid; i < dcnt; i += 256) lcur[i] = off[d0 + i];
  __syncthreads();
  int pb = off[d0], pe = off[d0 + dcnt];
  for (int p = pb + tid; p < pe; p += 256){
    unsigned int k = key[p];
    int dl = (int)(k >> 18);
    unsigned int s = k & 0x3FFFFu;
    int q14 = (int)(val[p]*16383.f + 0.5f);
    if (q14 > 16383) q14 = 16383;
    int q = atomicAdd(&lcur[dl], 1);
    packed[q] = (s << 14) | (unsigned int)q14;
  }
}

// ---------------- DCCF spmm gather (packed CSR) ----------------
__global__ __launch_bounds__(256) void k_spmm_gp(const int* __restrict__ off,
        const unsigned int* __restrict__ packed,
        const float* __restrict__ cur, float* __restrict__ gnn){
  int wv = threadIdx.x >> 6, lane = threadIdx.x & 63;
  int node = blockIdx.x*4 + wv;
  if (node >= N_NODES) return;
  int b = off[node], e = off[node+1];
  int c4 = (lane & 15)*4, sl = lane >> 4;
  float ax=0.f, ay=0.f, az=0.f, aw=0.f;
  const float inv14 = 1.f/16383.f;
  for (int k = b; k < e; k += 4){
    int idx = k + sl;
    bool v = idx < e;
    unsigned int pk = v ? packed[idx] : 0u;
    int s = (int)(pk >> 14);
    float w = v ? (float)(pk & 16383u) * inv14 : 0.f;
    const float4 x = *(const float4*)&cur[s*DD + c4];
    ax += w*x.x; ay += w*x.y; az += w*x.z; aw += w*x.w;
  }
  ax += __shfl_xor(ax, 16, 64); ay += __shfl_xor(ay, 16, 64);
  az += __shfl_xor(az, 16, 64); aw += __shfl_xor(aw, 16, 64);
  ax += __shfl_xor(ax, 32, 64); ay += __shfl_xor(ay, 32, 64);
  az += __shfl_xor(az, 32, 64); aw += __shfl_xor(aw, 32, 64);
  if (lane < 16) *(float4*)&gnn[node*DD + c4] = make_float4(ax, ay, az, aw);
}

// ---------------- intent (unchanged tiled GEMM) ----------------
__global__ __launch_bounds__(256) void k_intent2(const float* __restrict__ intent,
        const float* __restrict__ gnn, float* __restrict__ cur, float* __restrict__ total,
        int base, int nrows){
  __shared__ float sB[64*132];
  __shared__ float sU[ROWS*132];
  int tid = threadIdx.x, tx = tid & 15, ty = tid >> 4;

  for (int i = tid; i < 2048; i += 256){
    int r = i >> 5, c = (i & 31) << 2;
    *(float4*)&sB[r*132 + c] = *(const float4*)&intent[r*128 + c];
  }
  {
    int r = tid & 31, q0 = tid >> 5;
    int rr = blockIdx.x*ROWS + r;
    int rowg = base + (rr < nrows ? rr : nrows - 1);
    for (int q = q0; q < 16; q += 8){
      float4 v = *(const float4*)&cur[rowg*DD + 4*q];
      sU[(4*q+0)*36 + r] = v.x;
      sU[(4*q+1)*36 + r] = v.y;
      sU[(4*q+2)*36 + r] = v.z;
      sU[(4*q+3)*36 + r] = v.w;
    }
  }
  __syncthreads();

  float w[2][8];
  #pragma unroll
  for (int i = 0; i < 2; ++i)
    #pragma unroll
    for (int k = 0; k < 8; ++k) w[i][k] = 0.f;
  for (int d = 0; d < 64; ++d){
    float2 a = *(const float2*)&sU[d*36 + 2*ty];
    float4 b0 = *(const float4*)&sB[d*132 + 8*tx];
    float4 b1 = *(const float4*)&sB[d*132 + 8*tx + 4];
    float bb[8] = {b0.x,b0.y,b0.z,b0.w,b1.x,b1.y,b1.z,b1.w};
    #pragma unroll
    for (int k = 0; k < 8; ++k){ w[0][k] += a.x*bb[k]; w[1][k] += a.y*bb[k]; }
  }

  float p[2][8];
  #pragma unroll
  for (int i = 0; i < 2; ++i){
    float mx = w[i][0];
    #pragma unroll
    for (int k = 1; k < 8; ++k) mx = fmaxf(mx, w[i][k]);
    mx = fmaxf(mx, __shfl_xor(mx, 1, 64));
    mx = fmaxf(mx, __shfl_xor(mx, 2, 64));
    mx = fmaxf(mx, __shfl_xor(mx, 4, 64));
    mx = fmaxf(mx, __shfl_xor(mx, 8, 64));
    float s = 0.f;
    #pragma unroll
    for (int k = 0; k < 8; ++k){ p[i][k] = __expf(w[i][k] - mx); s += p[i][k]; }
    s += __shfl_xor(s, 1, 64);
    s += __shfl_xor(s, 2, 64);
    s += __shfl_xor(s, 4, 64);
    s += __shfl_xor(s, 8, 64);
    float inv = 1.f / s;
    #pragma unroll
    for (int k = 0; k < 8; ++k) p[i][k] *= inv;
  }
  __syncthreads();
  #pragma unroll
  for (int i = 0; i < 2; ++i){
    *(float4*)&sU[(2*ty+i)*132 + 8*tx]     = make_float4(p[i][0],p[i][1],p[i][2],p[i][3]);
    *(float4*)&sU[(2*ty+i)*132 + 8*tx + 4] = make_float4(p[i][4],p[i][5],p[i][6],p[i][7]);
  }
  __syncthreads();

  float o[2][4];
  #pragma unroll
  for (int i = 0; i < 2; ++i)
    #pragma unroll
    for (int m = 0; m < 4; ++m) o[i][m] = 0.f;
  for (int q = 0; q < 32; ++q){
    float4 p0 = *(const float4*)&sU[(2*ty+0)*132 + 4*q];
    float4 p1 = *(const float4*)&sU[(2*ty+1)*132 + 4*q];
    #pragma unroll
    for (int m = 0; m < 4; ++m){
      float4 bl = *(const float4*)&sB[(4*tx+m)*132 + 4*q];
      o[0][m] += p0.x*bl.x + p0.y*bl.y + p0.z*bl.z + p0.w*bl.w;
      o[1][m] += p1.x*bl.x + p1.y*bl.y + p1.z*bl.z + p1.w*bl.w;
    }
  }

  #pragma unroll
  for (int i = 0; i < 2; ++i){
    int rr = blockIdx.x*ROWS + 2*ty + i;
    if (rr < nrows){
      int rowg = base + rr;
      float4 g = *(const float4*)&gnn[rowg*DD + 4*tx];
      float4 c = *(const float4*)&cur[rowg*DD + 4*tx];
      float4 t = *(const float4*)&total[rowg*DD + 4*tx];
      float4 cn = make_float4(g.x + o[i][0] + c.x, g.y + o[i][1] + c.y,
                              g.z + o[i][2] + c.z, g.w + o[i][3] + c.w);
      *(float4*)&cur[rowg*DD + 4*tx] = cn;
      *(float4*)&total[rowg*DD + 4*tx] =
          make_float4(t.x + cn.x, t.y + cn.y, t.z + cn.z, t.w + cn.w);
    }
  }
}

// ---------------- HAN ----------------
__device__ __forceinline__ void han_decode(int t, const int* mp_u, const int* mp_i,
                                           const int** sp, const int** dp, int* e, int* nb){
  if (t < 2*EU){
    int s = (t < EU) ? 0 : 1;
    *e = t - s*EU;
    *sp = mp_u + (long)s*2*EU; *dp = *sp + EU;
    *nb = s*N_USERS;
  } else {
    int t2 = t - 2*EU;
    int s = (t2 < EI) ? 0 : 1;
    *e = t2 - s*EI;
    *sp = mp_i + (long)s*2*EI; *dp = *sp + EI;
    *nb = 2*N_USERS + s*N_ITEMS;
  }
}

__global__ void k_han_hist(const int* __restrict__ mp_u, const int* __restrict__ mp_i,
                           int* __restrict__ degout, int* __restrict__ cnt){
  int t = blockIdx.x*256 + threadIdx.x;
  if (t >= E_HAN) return;
  const int *sp, *dp; int e, nb;
  han_decode(t, mp_u, mp_i, &sp, &dp, &e, &nb);
  atomicAdd(&degout[nb + sp[e]], 1);
  atomicAdd(&cnt[nb + dp[e]], 1);
}

__global__ __launch_bounds__(256) void k_part1_h(const int* __restrict__ mp_u,
        const int* __restrict__ mp_i, int* __restrict__ bcur,
        unsigned int* __restrict__ key){
  __shared__ int hist[NBH];
  __shared__ int lcur[NBH];
  int tid = threadIdx.x;
  const int CH = E_HAN/256;          // 18750
  int t0 = blockIdx.x*CH;
  for (int b = tid; b < NBH; b += 256) hist[b] = 0;
  __syncthreads();
  for (int i = tid; i < CH; i += 256){
    const int *sp, *dp; int e, nb;
    han_decode(t0 + i, mp_u, mp_i, &sp, &dp, &e, &nb);
    int gd = nb + dp[e];
    atomicAdd(&hist[gd >> 9], 1);
  }
  __syncthreads();
  for (int b = tid; b < NBH; b += 256)
    lcur[b] = atomicAdd(&bcur[b], hist[b]);
  __syncthreads();
  for (int i = tid; i < CH; i += 256){
    const int *sp, *dp; int e, nb;
    han_decode(t0 + i, mp_u, mp_i, &sp, &dp, &e, &nb);
    int gd = nb + dp[e];
    int gs = nb + sp[e];
    int p = atomicAdd(&lcur[gd >> 9], 1);
    key[p] = ((unsigned int)(gd & 511) << 19) | (unsigned int)gs;
  }
}

__global__ __launch_bounds__(256) void k_part2_h(const int* __restrict__ off,
        const unsigned int* __restrict__ key, int* __restrict__ ssrc){
  __shared__ int lcur[512];
  int b = blockIdx.x, tid = threadIdx.x;
  int d0 = b*512;
  int dcnt = min(512, NH - d0);
  for (int i = tid; i < dcnt; i += 256) lcur[i] = off[d0 + i];
  __syncthreads();
  int pb = off[d0], pe = off[d0 + dcnt];
  for (int p = pb + tid; p < pe; p += 256){
    unsigned int k = key[p];
    int dl = (int)(k >> 19);
    int gs = (int)(k & 0x7FFFFu);
    int q = atomicAdd(&lcur[dl], 1);
    ssrc[q] = gs;
  }
}

// gtab[gsrc] = bf16( invdeg(degout[gsrc]) * feat[gsrc] )
__global__ void k_gtab(const int* __restrict__ degout, const float* __restrict__ fu,
                       const float* __restrict__ fi, unsigned short* __restrict__ gtab){
  int i = blockIdx.x*256 + threadIdx.x;
  if (i >= NH*DD) return;
  int n = i >> 6, d = i & 63;
  float f;
  if (n < 2*N_USERS){
    int local = (n < N_USERS) ? n : n - N_USERS;
    f = fu[local*DD + d];
  } else {
    int m = n - 2*N_USERS;
    int local = (m < N_ITEMS) ? m : m - N_ITEMS;
    f = fi[local*DD + d];
  }
  gtab[i] = f2b(invdeg((float)degout[n]) * f);
}

// z[g] (bf16) = invdeg(deg_in[g]) * sum gtab[src]
__global__ __launch_bounds__(256) void k_han_gb(const int* __restrict__ off,
        const int* __restrict__ ssrc, const int* __restrict__ cnt,
        const unsigned short* __restrict__ gtab, unsigned short* __restrict__ zb){
  int wv = threadIdx.x >> 6, lane = threadIdx.x & 63;
  int g = blockIdx.x*4 + wv;
  if (g >= NH) return;
  int b = off[g], e = off[g+1];
  int c4 = (lane & 15)*4, sl = lane >> 4;
  float ax=0.f, ay=0.f, az=0.f, aw=0.f;
  for (int k = b; k < e; k += 4){
    int idx = k + sl;
    bool v = idx < e;
    int s = v ? ssrc[idx] : 0;
    ushort4 u = *(const ushort4*)&gtab[s*DD + c4];
    float m = v ? 1.f : 0.f;
    ax += m*b2f(u.x); ay += m*b2f(u.y); az += m*b2f(u.z); aw += m*b2f(u.w);
  }
  ax += __shfl_xor(ax, 16, 64); ay += __shfl_xor(ay, 16, 64);
  az += __shfl_xor(az, 16, 64); aw += __shfl_xor(aw, 16, 64);
  ax += __shfl_xor(ax, 32, 64); ay += __shfl_xor(ay, 32, 64);
  az += __shfl_xor(az, 32, 64); aw += __shfl_xor(aw, 32, 64);
  if (lane < 16){
    float win = invdeg((float)cnt[g]);
    ushort4 o;
    o.x = f2b(win*ax); o.y = f2b(win*ay); o.z = f2b(win*az); o.w = f2b(win*aw);
    *(ushort4*)&zb[g*DD + c4] = o;
  }
}

// semantic attention reduction (bf16 z input)
__global__ __launch_bounds__(256) void k_sem2(const float* __restrict__ W1,
        const float* __restrict__ b1, const float* __restrict__ w2,
        const unsigned short* __restrict__ z, int nn, float* __restrict__ wsum){
  __shared__ float sW[64*132];
  __shared__ float sA[64*36];
  __shared__ float sBias[128], sV[128];
  __shared__ float red[2];
  int tid = threadIdx.x, tx = tid & 15, ty = tid >> 4;

  for (int i = tid; i < 2048; i += 256){
    int r = i >> 5, c = (i & 31) << 2;
    *(float4*)&sW[r*132 + c] = *(const float4*)&W1[r*128 + c];
  }
  if (tid < 128){ sBias[tid] = b1[tid]; sV[tid] = w2[tid]; }
  if (tid < 2) red[tid] = 0.f;

  for (int m = 0; m < 2; ++m){
    __syncthreads();
    {
      int r = tid & 31, q0 = tid >> 5;
      int rr = blockIdx.x*ROWS + r;
      int rowg = (rr < nn ? rr : nn - 1) + m*nn;
      for (int q = q0; q < 16; q += 8){
        ushort4 v = *(const ushort4*)&z[(long)rowg*DD + 4*q];
        sA[(4*q+0)*36 + r] = b2f(v.x);
        sA[(4*q+1)*36 + r] = b2f(v.y);
        sA[(4*q+2)*36 + r] = b2f(v.z);
        sA[(4*q+3)*36 + r] = b2f(v.w);
      }
    }
    __syncthreads();

    float w[2][8];
    #pragma unroll
    for (int i = 0; i < 2; ++i)
      #pragma unroll
      for (int k = 0; k < 8; ++k) w[i][k] = sBias[8*tx + k];
    for (int d = 0; d < 64; ++d){
      float2 a = *(const float2*)&sA[d*36 + 2*ty];
      float4 b0 = *(const float4*)&sW[d*132 + 8*tx];
      float4 b4 = *(const float4*)&sW[d*132 + 8*tx + 4];
      float bb[8] = {b0.x,b0.y,b0.z,b0.w,b4.x,b4.y,b4.z,b4.w};
      #pragma unroll
      for (int k = 0; k < 8; ++k){ w[0][k] += a.x*bb[k]; w[1][k] += a.y*bb[k]; }
    }
    float part = 0.f;
    #pragma unroll
    for (int i = 0; i < 2; ++i){
      int rr = blockIdx.x*ROWS + 2*ty + i;
      if (rr < nn){
        #pragma unroll
        for (int k = 0; k < 8; ++k) part += tanh_fast(w[i][k]) * sV[8*tx + k];
      }
    }
    part += __shfl_xor(part, 1, 64);
    part += __shfl_xor(part, 2, 64);
    part += __shfl_xor(part, 4, 64);
    part += __shfl_xor(part, 8, 64);
    part += __shfl_xor(part, 16, 64);
    part += __shfl_xor(part, 32, 64);
    if ((tid & 63) == 0) atomicAdd(&red[m], part);
  }
  __syncthreads();
  if (tid < 2) atomicAdd(&wsum[tid], red[tid]);
}

__global__ void k_beta(const float* __restrict__ wsum, float* __restrict__ beta){
  if (threadIdx.x == 0 && blockIdx.x == 0){
    float u0 = wsum[0] / (float)N_USERS, u1 = wsum[1] / (float)N_USERS;
    float m = fmaxf(u0, u1);
    float e0 = __expf(u0 - m), e1 = __expf(u1 - m);
    beta[0] = e0/(e0+e1); beta[1] = e1/(e0+e1);
    float i0 = wsum[2] / (float)N_ITEMS, i1 = wsum[3] / (float)N_ITEMS;
    m = fmaxf(i0, i1);
    e0 = __expf(i0 - m); e1 = __expf(i1 - m);
    beta[2] = e0/(e0+e1); beta[3] = e1/(e0+e1);
  }
}

__global__ void k_final(const float* __restrict__ total, const unsigned short* __restrict__ zb,
                        const float* __restrict__ beta, float* __restrict__ out){
  int i = blockIdx.x*256 + threadIdx.x;
  if (i >= N_NODES*DD) return;
  float h;
  if (i < N_USERS*DD)
    h = beta[0]*b2f(zb[i]) + beta[1]*b2f(zb[N_USERS*DD + i]);
  else {
    int j = i - N_USERS*DD;
    h = beta[2]*b2f(zb[2*N_USERS*DD + j]) + beta[3]*b2f(zb[(2*N_USERS + N_ITEMS)*DD + j]);
  }
  out[i] = 0.5f*total[i] + 0.5f*h;
}

extern "C" void kernel_launch(void* const* d_in, const int* in_sizes, int n_in,
                              void* d_out, int out_size, void* d_ws, size_t ws_size,
                              hipStream_t stream) {
  const int*   G_idx = (const int*)d_in[0];
  const float* G_val = (const float*)d_in[1];
  const float* fu    = (const float*)d_in[2];
  const float* fi    = (const float*)d_in[3];
  const float* u_int = (const float*)d_in[4];
  const float* i_int = (const float*)d_in[5];
  const int*   mp_u  = (const int*)d_in[6];
  const int*   mp_i  = (const int*)d_in[7];
  const float* uW1   = (const float*)d_in[8];
  const float* ub1   = (const float*)d_in[9];
  const float* uw2   = (const float*)d_in[10];
  const float* iW1   = (const float*)d_in[11];
  const float* ib1   = (const float*)d_in[12];
  const float* iw2   = (const float*)d_in[13];
  float* out = (float*)d_out;

  float* ws = (float*)d_ws;
  // Phase A (layers):
  float*        total  = ws;                                // [0, 9.6M)
  float*        cur    = ws + 9600000;                      // [9.6M, 19.2M)
  float*        gnn    = ws + 19200000;                     // [19.2M, 28.8M)
  unsigned int* keyG   = (unsigned int*)ws;                 // [0, 3.2M)  pre-init only
  float*        valG   = ws + 3200000;                      // [3.2M, 6.4M) pre-init only
  unsigned int* packG  = (unsigned int*)(ws + 28800000);    // [28.8M, 32.0M)
  int*          cntG   = (int*)(ws + 32000000);             // 150k
  int*          offG   = (int*)(ws + 32150000);             // 150001
  int*          bcurG  = (int*)(ws + 32301000);             // 293
  int*          bsumG  = (int*)(ws + 32302000);             // 586
  // Phase B (HAN):
  unsigned int* keyH   = (unsigned int*)(ws + 9600000);     // [9.6M,14.4M) dead before zb
  unsigned short* zb   = (unsigned short*)(ws + 9600000);   // [9.6M,19.2M) NH*64 bf16
  unsigned short* gtab = (unsigned short*)(ws + 19200000);  // [19.2M,28.8M) NH*64 bf16
  int*          ssrcH  = (int*)(ws + 28800000);             // [28.8M,33.6M)
  int*          degoH  = (int*)(ws + 33600000);             // 300k
  int*          cntH   = (int*)(ws + 33900000);             // 300k
  int*          offH   = (int*)(ws + 34200000);             // 300001
  int*          bcurH  = (int*)(ws + 34501000);             // 586
  int*          bsumH  = (int*)(ws + 34502000);             // 1172
  float*        wsum   = ws + 34504000;                     // 4
  float*        beta   = ws + 34504004;                     // 4

  hipMemsetAsync(cntG, 0, (size_t)N_NODES*sizeof(int), stream);
  hipMemsetAsync(wsum, 0, 4*sizeof(float), stream);

  // ---- G CSR build (dense two-phase partition; runs before k_init since
  //      keyG/valG alias total/cur regions) ----
  {
    int nbk = (N_NODES + 255)/256;
    k_hist<<<(E_G + 255)/256, 256, 0, stream>>>(G_idx, E_G, cntG);
    k_scan1<<<nbk, 256, 0, stream>>>(cntG, N_NODES, offG, bsumG);
    k_scan2<<<1, 256, 0, stream>>>(bsumG, nbk);
    k_scan3<<<nbk, 256, 0, stream>>>(offG, bsumG, N_NODES, E_G);
    k_binit<<<(NBG + 255)/256, 256, 0, stream>>>(bcurG, offG, NBG);
    k_part1_g<<<256, 256, 0, stream>>>(G_idx, G_val, bcurG, keyG, valG);
    k_part2_g<<<NBG, 256, 0, stream>>>(offG, keyG, valG, packG);
  }

  k_init<<<(N_NODES*DD + 255)/256, 256, 0, stream>>>(fu, fi, cur, total);

  // ---- DCCF layers ----
  for (int layer = 0; layer < 2; ++layer){
    k_spmm_gp<<<(N_NODES + 3)/4, 256, 0, stream>>>(offG, packG, cur, gnn);
    k_intent2<<<(N_USERS + ROWS-1)/ROWS, 256, 0, stream>>>(u_int, gnn, cur, total, 0, N_USERS);
    k_intent2<<<(N_ITEMS + ROWS-1)/ROWS, 256, 0, stream>>>(i_int, gnn, cur, total, N_USERS, N_ITEMS);
  }

  // ---- HAN: hist, scan, dense partition, bf16 table, gather ----
  {
    hipMemsetAsync(degoH, 0, (size_t)2*NH*sizeof(int), stream);  // degoH+cntH contiguous
    int nbk = (NH + 255)/256;
    k_han_hist<<<(E_HAN + 255)/256, 256, 0, stream>>>(mp_u, mp_i, degoH, cntH);
    k_scan1<<<nbk, 256, 0, stream>>>(cntH, NH, offH, bsumH);
    k_scan2<<<1, 256, 0, stream>>>(bsumH, nbk);
    k_scan3<<<nbk, 256, 0, stream>>>(offH, bsumH, NH, E_HAN);
    k_binit<<<(NBH + 255)/256, 256, 0, stream>>>(bcurH, offH, NBH);
    k_part1_h<<<256, 256, 0, stream>>>(mp_u, mp_i, bcurH, keyH);
    k_part2_h<<<NBH, 256, 0, stream>>>(offH, keyH, ssrcH);
    k_gtab<<<(NH*DD + 255)/256, 256, 0, stream>>>(degoH, fu, fi, gtab);
    k_han_gb<<<(NH + 3)/4, 256, 0, stream>>>(offH, ssrcH, cntH, gtab, zb);
  }

  // ---- semantic attention + combine ----
  k_sem2<<<(N_USERS + ROWS-1)/ROWS, 256, 0, stream>>>(uW1, ub1, uw2, zb, N_USERS, wsum);
  k_sem2<<<(N_ITEMS + ROWS-1)/ROWS, 256, 0, stream>>>(iW1, ib1, iw2,
      zb + (long)2*N_USERS*DD, N_ITEMS, wsum + 2);
  k_beta<<<1, 64, 0, stream>>>(wsum, beta);
  k_final<<<(N_NODES*DD + 255)/256, 256, 0, stream>>>(total, zb, beta, out);
}

// Round 7
// 1332.689 us; speedup vs baseline: 3.6089x; 1.3536x over previous
//
#include <hip/hip_runtime.h>
#include <hip/hip_bf16.h>
#include <math.h>

#define N_USERS 100000
#define N_ITEMS 50000
#define N_NODES 150000
#define DD 64
#define E_G 3200000
#define EU 1600000
#define EI 800000
#define E_HAN 4800000
#define NH 300000
#define NBG 293        // ceil(150000/512)
#define NBH 586        // ceil(300000/512)
#define ROWS 32

__device__ __forceinline__ float invdeg(float d){
  return d > 0.f ? rsqrtf(fmaxf(d, 1e-12f)) : 0.f;
}
__device__ __forceinline__ float tanh_fast(float x){
  float cx = fminf(15.f, fmaxf(-15.f, x));
  float t = __expf(2.f*cx);
  return (t - 1.f)/(t + 1.f);
}
__device__ __forceinline__ unsigned short f2b(float x){
  unsigned int b = __float_as_uint(x);
  b += 0x7FFFu + ((b >> 16) & 1u);
  return (unsigned short)(b >> 16);
}
__device__ __forceinline__ float b2f(unsigned short u){
  return __uint_as_float(((unsigned int)u) << 16);
}

__global__ void k_init(const float* __restrict__ fu, const float* __restrict__ fi,
                       float* __restrict__ cur, float* __restrict__ total){
  int i = blockIdx.x*256 + threadIdx.x;
  if (i >= N_NODES*DD) return;
  float v = (i < N_USERS*DD) ? fu[i] : fi[i - N_USERS*DD];
  cur[i] = v; total[i] = v;
}

// ---------------- generic scan helpers ----------------
// per-column exclusive scan of wh[256][nb]; colsum[b] = column total
__global__ __launch_bounds__(256) void k_colscan(int* __restrict__ wh, int nb,
                                                 int* __restrict__ colsum){
  __shared__ int s[256];
  int b = blockIdx.x, tid = threadIdx.x;
  int v = wh[tid*nb + b];
  s[tid] = v; __syncthreads();
  for (int o = 1; o < 256; o <<= 1){
    int t = (tid >= o) ? s[tid - o] : 0;
    __syncthreads();
    s[tid] += t;
    __syncthreads();
  }
  wh[tid*nb + b] = s[tid] - v;
  if (tid == 255) colsum[b] = s[255];
}

// single-block exclusive scan colsum[nb] -> bB[0..nb], bB[nb]=total
__global__ __launch_bounds__(256) void k_bscan(const int* __restrict__ colsum, int nb,
                                               int total, int* __restrict__ bB){
  __shared__ int s[256];
  __shared__ int carry;
  int tid = threadIdx.x;
  if (tid == 0) carry = 0;
  __syncthreads();
  for (int base = 0; base < nb; base += 256){
    int i = base + tid;
    int v = (i < nb) ? colsum[i] : 0;
    s[tid] = v; __syncthreads();
    for (int o = 1; o < 256; o <<= 1){
      int t = (tid >= o) ? s[tid - o] : 0;
      __syncthreads();
      s[tid] += t;
      __syncthreads();
    }
    int c = carry;
    if (i < nb) bB[i] = c + s[tid] - v;
    __syncthreads();
    if (tid == 255) carry = c + s[255];
    __syncthreads();
  }
  if (tid == 0) bB[nb] = total;
}

// ---------------- G build ----------------
__global__ __launch_bounds__(256) void k_h1_g(const int* __restrict__ gi,
                                              int* __restrict__ wh){
  __shared__ int h[NBG];
  int tid = threadIdx.x;
  for (int b = tid; b < NBG; b += 256) h[b] = 0;
  __syncthreads();
  int e0 = blockIdx.x*(E_G/256);
  for (int i = tid; i < E_G/256; i += 256)
    atomicAdd(&h[gi[e0 + i] >> 9], 1);
  __syncthreads();
  for (int b = tid; b < NBG; b += 256) wh[blockIdx.x*NBG + b] = h[b];
}

__global__ __launch_bounds__(256) void k_h2_g(const int* __restrict__ gi,
        const float* __restrict__ gv, const int* __restrict__ wh,
        const int* __restrict__ bB, uint2* __restrict__ kv){
  __shared__ int lcur[NBG];
  int tid = threadIdx.x, wg = blockIdx.x;
  for (int b = tid; b < NBG; b += 256) lcur[b] = bB[b] + wh[wg*NBG + b];
  __syncthreads();
  int e0 = wg*(E_G/256);
  for (int i = tid; i < E_G/256; i += 256){
    int e = e0 + i;
    int d = gi[e];
    int p = atomicAdd(&lcur[d >> 9], 1);
    uint2 r;
    r.x = ((unsigned)(d & 511) << 18) | (unsigned)gi[E_G + e];
    r.y = __float_as_uint(gv[e]);
    kv[p] = r;
  }
}

__global__ __launch_bounds__(256) void k_p2_g(const int* __restrict__ bB,
        const uint2* __restrict__ kv, int* __restrict__ off,
        unsigned int* __restrict__ packed){
  __shared__ int cnt[512], sc[512], lcur[512];
  int b = blockIdx.x, tid = threadIdx.x;
  int d0 = b << 9;
  int dcnt = min(512, N_NODES - d0);
  int pb = bB[b], pe = bB[b+1];
  for (int i = tid; i < 512; i += 256) cnt[i] = 0;
  __syncthreads();
  for (int p = pb + tid; p < pe; p += 256)
    atomicAdd(&cnt[kv[p].x >> 18], 1);
  __syncthreads();
  sc[tid] = cnt[tid]; sc[tid + 256] = cnt[tid + 256];
  __syncthreads();
  for (int o = 1; o < 512; o <<= 1){
    int a0 = (tid >= o) ? sc[tid - o] : 0;
    int a1 = sc[tid + 256 - o];
    __syncthreads();
    sc[tid] += a0; sc[tid + 256] += a1;
    __syncthreads();
  }
  for (int i = tid; i < 512; i += 256) lcur[i] = pb + sc[i] - cnt[i];
  for (int i = tid; i < dcnt; i += 256) off[d0 + i] = pb + sc[i] - cnt[i];
  if (tid == 0) off[d0 + dcnt] = pe;
  __syncthreads();
  for (int p = pb + tid; p < pe; p += 256){
    uint2 r = kv[p];
    int dl = (int)(r.x >> 18);
    unsigned int s = r.x & 0x3FFFFu;
    float v = __uint_as_float(r.y);
    int q14 = (int)(v*16383.f + 0.5f);
    if (q14 > 16383) q14 = 16383;
    int q = atomicAdd(&lcur[dl], 1);
    packed[q] = (s << 14) | (unsigned int)q14;
  }
}

// ---------------- DCCF spmm gather (packed CSR) ----------------
__global__ __launch_bounds__(256) void k_spmm_gp(const int* __restrict__ off,
        const unsigned int* __restrict__ packed,
        const float* __restrict__ cur, float* __restrict__ gnn){
  int wv = threadIdx.x >> 6, lane = threadIdx.x & 63;
  int node = blockIdx.x*4 + wv;
  if (node >= N_NODES) return;
  int b = off[node], e = off[node+1];
  int c4 = (lane & 15)*4, sl = lane >> 4;
  float ax=0.f, ay=0.f, az=0.f, aw=0.f;
  const float inv14 = 1.f/16383.f;
  for (int k = b; k < e; k += 4){
    int idx = k + sl;
    bool v = idx < e;
    unsigned int pk = v ? packed[idx] : 0u;
    int s = (int)(pk >> 14);
    float w = v ? (float)(pk & 16383u) * inv14 : 0.f;
    const float4 x = *(const float4*)&cur[s*DD + c4];
    ax += w*x.x; ay += w*x.y; az += w*x.z; aw += w*x.w;
  }
  ax += __shfl_xor(ax, 16, 64); ay += __shfl_xor(ay, 16, 64);
  az += __shfl_xor(az, 16, 64); aw += __shfl_xor(aw, 16, 64);
  ax += __shfl_xor(ax, 32, 64); ay += __shfl_xor(ay, 32, 64);
  az += __shfl_xor(az, 32, 64); aw += __shfl_xor(aw, 32, 64);
  if (lane < 16) *(float4*)&gnn[node*DD + c4] = make_float4(ax, ay, az, aw);
}

// ---------------- intent (tiled GEMM) ----------------
__global__ __launch_bounds__(256) void k_intent2(const float* __restrict__ intent,
        const float* __restrict__ gnn, float* __restrict__ cur, float* __restrict__ total,
        int base, int nrows){
  __shared__ float sB[64*132];
  __shared__ float sU[ROWS*132];
  int tid = threadIdx.x, tx = tid & 15, ty = tid >> 4;

  for (int i = tid; i < 2048; i += 256){
    int r = i >> 5, c = (i & 31) << 2;
    *(float4*)&sB[r*132 + c] = *(const float4*)&intent[r*128 + c];
  }
  {
    int r = tid & 31, q0 = tid >> 5;
    int rr = blockIdx.x*ROWS + r;
    int rowg = base + (rr < nrows ? rr : nrows - 1);
    for (int q = q0; q < 16; q += 8){
      float4 v = *(const float4*)&cur[rowg*DD + 4*q];
      sU[(4*q+0)*36 + r] = v.x;
      sU[(4*q+1)*36 + r] = v.y;
      sU[(4*q+2)*36 + r] = v.z;
      sU[(4*q+3)*36 + r] = v.w;
    }
  }
  __syncthreads();

  float w[2][8];
  #pragma unroll
  for (int i = 0; i < 2; ++i)
    #pragma unroll
    for (int k = 0; k < 8; ++k) w[i][k] = 0.f;
  for (int d = 0; d < 64; ++d){
    float2 a = *(const float2*)&sU[d*36 + 2*ty];
    float4 b0 = *(const float4*)&sB[d*132 + 8*tx];
    float4 b1 = *(const float4*)&sB[d*132 + 8*tx + 4];
    float bb[8] = {b0.x,b0.y,b0.z,b0.w,b1.x,b1.y,b1.z,b1.w};
    #pragma unroll
    for (int k = 0; k < 8; ++k){ w[0][k] += a.x*bb[k]; w[1][k] += a.y*bb[k]; }
  }

  float p[2][8];
  #pragma unroll
  for (int i = 0; i < 2; ++i){
    float mx = w[i][0];
    #pragma unroll
    for (int k = 1; k < 8; ++k) mx = fmaxf(mx, w[i][k]);
    mx = fmaxf(mx, __shfl_xor(mx, 1, 64));
    mx = fmaxf(mx, __shfl_xor(mx, 2, 64));
    mx = fmaxf(mx, __shfl_xor(mx, 4, 64));
    mx = fmaxf(mx, __shfl_xor(mx, 8, 64));
    float s = 0.f;
    #pragma unroll
    for (int k = 0; k < 8; ++k){ p[i][k] = __expf(w[i][k] - mx); s += p[i][k]; }
    s += __shfl_xor(s, 1, 64);
    s += __shfl_xor(s, 2, 64);
    s += __shfl_xor(s, 4, 64);
    s += __shfl_xor(s, 8, 64);
    float inv = 1.f / s;
    #pragma unroll
    for (int k = 0; k < 8; ++k) p[i][k] *= inv;
  }
  __syncthreads();
  #pragma unroll
  for (int i = 0; i < 2; ++i){
    *(float4*)&sU[(2*ty+i)*132 + 8*tx]     = make_float4(p[i][0],p[i][1],p[i][2],p[i][3]);
    *(float4*)&sU[(2*ty+i)*132 + 8*tx + 4] = make_float4(p[i][4],p[i][5],p[i][6],p[i][7]);
  }
  __syncthreads();

  float o[2][4];
  #pragma unroll
  for (int i = 0; i < 2; ++i)
    #pragma unroll
    for (int m = 0; m < 4; ++m) o[i][m] = 0.f;
  for (int q = 0; q < 32; ++q){
    float4 p0 = *(const float4*)&sU[(2*ty+0)*132 + 4*q];
    float4 p1 = *(const float4*)&sU[(2*ty+1)*132 + 4*q];
    #pragma unroll
    for (int m = 0; m < 4; ++m){
      float4 bl = *(const float4*)&sB[(4*tx+m)*132 + 4*q];
      o[0][m] += p0.x*bl.x + p0.y*bl.y + p0.z*bl.z + p0.w*bl.w;
      o[1][m] += p1.x*bl.x + p1.y*bl.y + p1.z*bl.z + p1.w*bl.w;
    }
  }

  #pragma unroll
  for (int i = 0; i < 2; ++i){
    int rr = blockIdx.x*ROWS + 2*ty + i;
    if (rr < nrows){
      int rowg = base + rr;
      float4 g = *(const float4*)&gnn[rowg*DD + 4*tx];
      float4 c = *(const float4*)&cur[rowg*DD + 4*tx];
      float4 t = *(const float4*)&total[rowg*DD + 4*tx];
      float4 cn = make_float4(g.x + o[i][0] + c.x, g.y + o[i][1] + c.y,
                              g.z + o[i][2] + c.z, g.w + o[i][3] + c.w);
      *(float4*)&cur[rowg*DD + 4*tx] = cn;
      *(float4*)&total[rowg*DD + 4*tx] =
          make_float4(t.x + cn.x, t.y + cn.y, t.z + cn.z, t.w + cn.w);
    }
  }
}

// ---------------- HAN build ----------------
__device__ __forceinline__ void han_decode(int t, const int* mp_u, const int* mp_i,
                                           int* gs, int* gd){
  if (t < 2*EU){
    int s = (t < EU) ? 0 : 1;
    int e = t - s*EU;
    const int* sp = mp_u + (long)s*2*EU;
    int nb = s*N_USERS;
    *gs = nb + sp[e]; *gd = nb + sp[EU + e];
  } else {
    int t2 = t - 2*EU;
    int s = (t2 < EI) ? 0 : 1;
    int e = t2 - s*EI;
    const int* sp = mp_i + (long)s*2*EI;
    int nb = 2*N_USERS + s*N_ITEMS;
    *gs = nb + sp[e]; *gd = nb + sp[EI + e];
  }
}

__global__ __launch_bounds__(256) void k_h1_h(const int* __restrict__ mp_u,
        const int* __restrict__ mp_i, int* __restrict__ whD, int* __restrict__ whS){
  __shared__ int hd[NBH], hs[NBH];
  int tid = threadIdx.x;
  for (int b = tid; b < NBH; b += 256){ hd[b] = 0; hs[b] = 0; }
  __syncthreads();
  int t0 = blockIdx.x*(E_HAN/256);
  for (int i = tid; i < E_HAN/256; i += 256){
    int gs, gd;
    han_decode(t0 + i, mp_u, mp_i, &gs, &gd);
    atomicAdd(&hd[gd >> 9], 1);
    atomicAdd(&hs[gs >> 9], 1);
  }
  __syncthreads();
  for (int b = tid; b < NBH; b += 256){
    whD[blockIdx.x*NBH + b] = hd[b];
    whS[blockIdx.x*NBH + b] = hs[b];
  }
}

__global__ __launch_bounds__(256) void k_h2_h(const int* __restrict__ mp_u,
        const int* __restrict__ mp_i, const int* __restrict__ whD,
        const int* __restrict__ whS, const int* __restrict__ bBD,
        const int* __restrict__ bBS, unsigned int* __restrict__ keyD,
        int* __restrict__ keyS){
  __shared__ int lcD[NBH], lcS[NBH];
  int tid = threadIdx.x, wg = blockIdx.x;
  for (int b = tid; b < NBH; b += 256){
    lcD[b] = bBD[b] + whD[wg*NBH + b];
    lcS[b] = bBS[b] + whS[wg*NBH + b];
  }
  __syncthreads();
  int t0 = wg*(E_HAN/256);
  for (int i = tid; i < E_HAN/256; i += 256){
    int gs, gd;
    han_decode(t0 + i, mp_u, mp_i, &gs, &gd);
    int pD = atomicAdd(&lcD[gd >> 9], 1);
    keyD[pD] = ((unsigned)(gd & 511) << 19) | (unsigned)gs;
    int pS = atomicAdd(&lcS[gs >> 9], 1);
    keyS[pS] = gs;
  }
}

__global__ __launch_bounds__(256) void k_p2_h(const int* __restrict__ bB,
        const unsigned int* __restrict__ key, int* __restrict__ off,
        int* __restrict__ ssrc){
  __shared__ int cnt[512], sc[512], lcur[512];
  int b = blockIdx.x, tid = threadIdx.x;
  int d0 = b << 9;
  int dcnt = min(512, NH - d0);
  int pb = bB[b], pe = bB[b+1];
  for (int i = tid; i < 512; i += 256) cnt[i] = 0;
  __syncthreads();
  for (int p = pb + tid; p < pe; p += 256)
    atomicAdd(&cnt[key[p] >> 19], 1);
  __syncthreads();
  sc[tid] = cnt[tid]; sc[tid + 256] = cnt[tid + 256];
  __syncthreads();
  for (int o = 1; o < 512; o <<= 1){
    int a0 = (tid >= o) ? sc[tid - o] : 0;
    int a1 = sc[tid + 256 - o];
    __syncthreads();
    sc[tid] += a0; sc[tid + 256] += a1;
    __syncthreads();
  }
  for (int i = tid; i < 512; i += 256) lcur[i] = pb + sc[i] - cnt[i];
  for (int i = tid; i < dcnt; i += 256) off[d0 + i] = pb + sc[i] - cnt[i];
  if (tid == 0) off[d0 + dcnt] = pe;
  __syncthreads();
  for (int p = pb + tid; p < pe; p += 256){
    unsigned int k = key[p];
    int dl = (int)(k >> 19);
    int q = atomicAdd(&lcur[dl], 1);
    ssrc[q] = (int)(k & 0x7FFFFu);
  }
}

__global__ __launch_bounds__(256) void k_cnt_hs(const int* __restrict__ bB,
        const int* __restrict__ keyS, int* __restrict__ dego){
  __shared__ int cnt[512];
  int b = blockIdx.x, tid = threadIdx.x;
  int d0 = b << 9;
  int dcnt = min(512, NH - d0);
  int pb = bB[b], pe = bB[b+1];
  for (int i = tid; i < 512; i += 256) cnt[i] = 0;
  __syncthreads();
  for (int p = pb + tid; p < pe; p += 256)
    atomicAdd(&cnt[keyS[p] & 511], 1);
  __syncthreads();
  for (int i = tid; i < dcnt; i += 256) dego[d0 + i] = cnt[i];
}

// gtab[gsrc] = bf16( invdeg(degout[gsrc]) * feat[gsrc] )
__global__ void k_gtab(const int* __restrict__ degout, const float* __restrict__ fu,
                       const float* __restrict__ fi, unsigned short* __restrict__ gtab){
  int i = blockIdx.x*256 + threadIdx.x;
  if (i >= NH*DD) return;
  int n = i >> 6, d = i & 63;
  float f;
  if (n < 2*N_USERS){
    int local = (n < N_USERS) ? n : n - N_USERS;
    f = fu[local*DD + d];
  } else {
    int m = n - 2*N_USERS;
    int local = (m < N_ITEMS) ? m : m - N_ITEMS;
    f = fi[local*DD + d];
  }
  gtab[i] = f2b(invdeg((float)degout[n]) * f);
}

// z[g] (bf16) = invdeg(deg_in[g]) * sum gtab[src]; deg_in = off diff
__global__ __launch_bounds__(256) void k_han_gb(const int* __restrict__ off,
        const int* __restrict__ ssrc, const unsigned short* __restrict__ gtab,
        unsigned short* __restrict__ zb){
  int wv = threadIdx.x >> 6, lane = threadIdx.x & 63;
  int g = blockIdx.x*4 + wv;
  if (g >= NH) return;
  int b = off[g], e = off[g+1];
  int c4 = (lane & 15)*4, sl = lane >> 4;
  float ax=0.f, ay=0.f, az=0.f, aw=0.f;
  for (int k = b; k < e; k += 4){
    int idx = k + sl;
    bool v = idx < e;
    int s = v ? ssrc[idx] : 0;
    ushort4 u = *(const ushort4*)&gtab[s*DD + c4];
    float m = v ? 1.f : 0.f;
    ax += m*b2f(u.x); ay += m*b2f(u.y); az += m*b2f(u.z); aw += m*b2f(u.w);
  }
  ax += __shfl_xor(ax, 16, 64); ay += __shfl_xor(ay, 16, 64);
  az += __shfl_xor(az, 16, 64); aw += __shfl_xor(aw, 16, 64);
  ax += __shfl_xor(ax, 32, 64); ay += __shfl_xor(ay, 32, 64);
  az += __shfl_xor(az, 32, 64); aw += __shfl_xor(aw, 32, 64);
  if (lane < 16){
    float win = invdeg((float)(e - b));
    ushort4 o;
    o.x = f2b(win*ax); o.y = f2b(win*ay); o.z = f2b(win*az); o.w = f2b(win*aw);
    *(ushort4*)&zb[g*DD + c4] = o;
  }
}

// semantic attention reduction (bf16 z input)
__global__ __launch_bounds__(256) void k_sem2(const float* __restrict__ W1,
        const float* __restrict__ b1, const float* __restrict__ w2,
        const unsigned short* __restrict__ z, int nn, float* __restrict__ wsum){
  __shared__ float sW[64*132];
  __shared__ float sA[64*36];
  __shared__ float sBias[128], sV[128];
  __shared__ float red[2];
  int tid = threadIdx.x, tx = tid & 15, ty = tid >> 4;

  for (int i = tid; i < 2048; i += 256){
    int r = i >> 5, c = (i & 31) << 2;
    *(float4*)&sW[r*132 + c] = *(const float4*)&W1[r*128 + c];
  }
  if (tid < 128){ sBias[tid] = b1[tid]; sV[tid] = w2[tid]; }
  if (tid < 2) red[tid] = 0.f;

  for (int m = 0; m < 2; ++m){
    __syncthreads();
    {
      int r = tid & 31, q0 = tid >> 5;
      int rr = blockIdx.x*ROWS + r;
      int rowg = (rr < nn ? rr : nn - 1) + m*nn;
      for (int q = q0; q < 16; q += 8){
        ushort4 v = *(const ushort4*)&z[(long)rowg*DD + 4*q];
        sA[(4*q+0)*36 + r] = b2f(v.x);
        sA[(4*q+1)*36 + r] = b2f(v.y);
        sA[(4*q+2)*36 + r] = b2f(v.z);
        sA[(4*q+3)*36 + r] = b2f(v.w);
      }
    }
    __syncthreads();

    float w[2][8];
    #pragma unroll
    for (int i = 0; i < 2; ++i)
      #pragma unroll
      for (int k = 0; k < 8; ++k) w[i][k] = sBias[8*tx + k];
    for (int d = 0; d < 64; ++d){
      float2 a = *(const float2*)&sA[d*36 + 2*ty];
      float4 b0 = *(const float4*)&sW[d*132 + 8*tx];
      float4 b4 = *(const float4*)&sW[d*132 + 8*tx + 4];
      float bb[8] = {b0.x,b0.y,b0.z,b0.w,b4.x,b4.y,b4.z,b4.w};
      #pragma unroll
      for (int k = 0; k < 8; ++k){ w[0][k] += a.x*bb[k]; w[1][k] += a.y*bb[k]; }
    }
    float part = 0.f;
    #pragma unroll
    for (int i = 0; i < 2; ++i){
      int rr = blockIdx.x*ROWS + 2*ty + i;
      if (rr < nn){
        #pragma unroll
        for (int k = 0; k < 8; ++k) part += tanh_fast(w[i][k]) * sV[8*tx + k];
      }
    }
    part += __shfl_xor(part, 1, 64);
    part += __shfl_xor(part, 2, 64);
    part += __shfl_xor(part, 4, 64);
    part += __shfl_xor(part, 8, 64);
    part += __shfl_xor(part, 16, 64);
    part += __shfl_xor(part, 32, 64);
    if ((tid & 63) == 0) atomicAdd(&red[m], part);
  }
  __syncthreads();
  if (tid < 2) atomicAdd(&wsum[tid], red[tid]);
}

__global__ void k_beta(const float* __restrict__ wsum, float* __restrict__ beta){
  if (threadIdx.x == 0 && blockIdx.x == 0){
    float u0 = wsum[0] / (float)N_USERS, u1 = wsum[1] / (float)N_USERS;
    float m = fmaxf(u0, u1);
    float e0 = __expf(u0 - m), e1 = __expf(u1 - m);
    beta[0] = e0/(e0+e1); beta[1] = e1/(e0+e1);
    float i0 = wsum[2] / (float)N_ITEMS, i1 = wsum[3] / (float)N_ITEMS;
    m = fmaxf(i0, i1);
    e0 = __expf(i0 - m); e1 = __expf(i1 - m);
    beta[2] = e0/(e0+e1); beta[3] = e1/(e0+e1);
  }
}

__global__ void k_final(const float* __restrict__ total, const unsigned short* __restrict__ zb,
                        const float* __restrict__ beta, float* __restrict__ out){
  int i = blockIdx.x*256 + threadIdx.x;
  if (i >= N_NODES*DD) return;
  float h;
  if (i < N_USERS*DD)
    h = beta[0]*b2f(zb[i]) + beta[1]*b2f(zb[N_USERS*DD + i]);
  else {
    int j = i - N_USERS*DD;
    h = beta[2]*b2f(zb[2*N_USERS*DD + j]) + beta[3]*b2f(zb[(2*N_USERS + N_ITEMS)*DD + j]);
  }
  out[i] = 0.5f*total[i] + 0.5f*h;
}

extern "C" void kernel_launch(void* const* d_in, const int* in_sizes, int n_in,
                              void* d_out, int out_size, void* d_ws, size_t ws_size,
                              hipStream_t stream) {
  const int*   G_idx = (const int*)d_in[0];
  const float* G_val = (const float*)d_in[1];
  const float* fu    = (const float*)d_in[2];
  const float* fi    = (const float*)d_in[3];
  const float* u_int = (const float*)d_in[4];
  const float* i_int = (const float*)d_in[5];
  const int*   mp_u  = (const int*)d_in[6];
  const int*   mp_i  = (const int*)d_in[7];
  const float* uW1   = (const float*)d_in[8];
  const float* ub1   = (const float*)d_in[9];
  const float* uw2   = (const float*)d_in[10];
  const float* iW1   = (const float*)d_in[11];
  const float* ib1   = (const float*)d_in[12];
  const float* iw2   = (const float*)d_in[13];
  float* out = (float*)d_out;

  float* ws = (float*)d_ws;
  // Phase A (G build + layers):
  float*        total  = ws;                                // [0, 9.6M)
  float*        cur    = ws + 9600000;                      // [9.6M, 19.2M)
  float*        gnn    = ws + 19200000;                     // [19.2M, 28.8M)
  uint2*        kvG    = (uint2*)ws;                        // [0, 6.4M) dead before k_init
  unsigned int* packG  = (unsigned int*)(ws + 28800000);    // [28.8M, 32.0M)
  int*          offG   = (int*)(ws + 33700000);             // 150001
  int*          whG    = (int*)(ws + 34930000);             // 256*293 = 75008
  int*          colG   = (int*)(ws + 35018000);             // 293
  int*          bBG    = (int*)(ws + 35019000);             // 294
  // Phase B (HAN):
  unsigned int* keyH   = (unsigned int*)(ws + 9600000);     // [9.6M,14.4M) dead before zb
  unsigned short* zb   = (unsigned short*)(ws + 9600000);   // [9.6M,19.2M)
  int*          keyS   = (int*)(ws + 19200000);             // [19.2M,24M) dead before gtab
  unsigned short* gtab = (unsigned short*)(ws + 19200000);  // [19.2M,28.8M)
  int*          ssrcH  = (int*)(ws + 28800000);             // [28.8M,33.6M)
  int*          degoH  = (int*)(ws + 34000000);             // 300k
  int*          offH   = (int*)(ws + 34300000);             // 300001
  int*          whH    = (int*)(ws + 34610000);             // 256*586 = 150016
  int*          whS    = (int*)(ws + 34770000);             // 150016
  int*          colH   = (int*)(ws + 35010000);             // 586
  int*          bBH    = (int*)(ws + 35012000);             // 587
  int*          colS   = (int*)(ws + 35014000);             // 586
  int*          bBS    = (int*)(ws + 35016000);             // 587
  float*        wsum   = ws + 35030000;                     // 4
  float*        beta   = ws + 35030004;                     // 4

  hipMemsetAsync(wsum, 0, 4*sizeof(float), stream);

  // ---- G CSR build (atomic-free partition; before k_init: kvG aliases total/cur) ----
  k_h1_g<<<256, 256, 0, stream>>>(G_idx, whG);
  k_colscan<<<NBG, 256, 0, stream>>>(whG, NBG, colG);
  k_bscan<<<1, 256, 0, stream>>>(colG, NBG, E_G, bBG);
  k_h2_g<<<256, 256, 0, stream>>>(G_idx, G_val, whG, bBG, kvG);
  k_p2_g<<<NBG, 256, 0, stream>>>(bBG, kvG, offG, packG);

  k_init<<<(N_NODES*DD + 255)/256, 256, 0, stream>>>(fu, fi, cur, total);

  // ---- DCCF layers ----
  for (int layer = 0; layer < 2; ++layer){
    k_spmm_gp<<<(N_NODES + 3)/4, 256, 0, stream>>>(offG, packG, cur, gnn);
    k_intent2<<<(N_USERS + ROWS-1)/ROWS, 256, 0, stream>>>(u_int, gnn, cur, total, 0, N_USERS);
    k_intent2<<<(N_ITEMS + ROWS-1)/ROWS, 256, 0, stream>>>(i_int, gnn, cur, total, N_USERS, N_ITEMS);
  }

  // ---- HAN build (atomic-free) + gather ----
  k_h1_h<<<256, 256, 0, stream>>>(mp_u, mp_i, whH, whS);
  k_colscan<<<NBH, 256, 0, stream>>>(whH, NBH, colH);
  k_bscan<<<1, 256, 0, stream>>>(colH, NBH, E_HAN, bBH);
  k_colscan<<<NBH, 256, 0, stream>>>(whS, NBH, colS);
  k_bscan<<<1, 256, 0, stream>>>(colS, NBH, E_HAN, bBS);
  k_h2_h<<<256, 256, 0, stream>>>(mp_u, mp_i, whH, whS, bBH, bBS, keyH, keyS);
  k_p2_h<<<NBH, 256, 0, stream>>>(bBH, keyH, offH, ssrcH);
  k_cnt_hs<<<NBH, 256, 0, stream>>>(bBS, keyS, degoH);
  k_gtab<<<(NH*DD + 255)/256, 256, 0, stream>>>(degoH, fu, fi, gtab);
  k_han_gb<<<(NH + 3)/4, 256, 0, stream>>>(offH, ssrcH, gtab, zb);

  // ---- semantic attention + combine ----
  k_sem2<<<(N_USERS + ROWS-1)/ROWS, 256, 0, stream>>>(uW1, ub1, uw2, zb, N_USERS, wsum);
  k_sem2<<<(N_ITEMS + ROWS-1)/ROWS, 256, 0, stream>>>(iW1, ib1, iw2,
      zb + (long)2*N_USERS*DD, N_ITEMS, wsum + 2);
  k_beta<<<1, 64, 0, stream>>>(wsum, beta);
  k_final<<<(N_NODES*DD + 255)/256, 256, 0, stream>>>(total, zb, beta, out);
}